// Round 3
// baseline (425.519 us; speedup 1.0000x reference)
//
#include <hip/hip_runtime.h>
#include <hip/hip_bf16.h>

#define N_ 384
#define C_ 128
#define M_ (N_*N_)   // 147456 rows (i*384+j)

typedef __attribute__((ext_vector_type(8))) short bf16x8_t;
typedef __attribute__((ext_vector_type(4))) float f32x4_t;
typedef unsigned int u32;
typedef unsigned short u16;
typedef unsigned long long u64;

__device__ __forceinline__ u16 f2bf(float f) {
  u32 u = __builtin_bit_cast(u32, f);
  u32 r = (u + 0x7FFFu + ((u >> 16) & 1u)) >> 16;
  return (u16)r;
}
__device__ __forceinline__ float bf2f(u16 h) {
  u32 u = ((u32)h) << 16;
  return __builtin_bit_cast(float, u);
}

// ---------------- prep kernels ----------------
__global__ __launch_bounds__(256) void k_prep1(const float* __restrict__ lg, const float* __restrict__ rg,
    const float* __restrict__ Wl, const float* __restrict__ Wr, const float* __restrict__ Wg,
    const float* __restrict__ Wo, u16* __restrict__ wcat, u16* __restrict__ wot) {
  int idx = blockIdx.x*256 + threadIdx.x;
  if (idx < 49152) {
    int n = idx >> 7, k = idx & 127;
    float v;
    if (n < 128)      v = lg[k] * Wl[k*128 + n];
    else if (n < 256) v = rg[k] * Wr[k*128 + (n-128)];
    else              v = Wg[k*128 + (n-256)];
    wcat[idx] = f2bf(v);
  } else {
    int i2 = idx - 49152;           // < 16384
    int c = i2 >> 7, h = i2 & 127;
    wot[i2] = f2bf(Wo[h*128 + c]);
  }
}

__global__ __launch_bounds__(512) void k_prep2(const float* __restrict__ lb, const float* __restrict__ rb,
    const float* __restrict__ Wl, const float* __restrict__ Wr, const float* __restrict__ Wg,
    const float* __restrict__ bl, const float* __restrict__ br, const float* __restrict__ bg,
    float* __restrict__ bcat, float* __restrict__ sg) {
  int t = threadIdx.x;
  if (blockIdx.x == 0) {
    if (t < 384) {
      float s = 0.f;
      if (t < 128)      { for (int k=0;k<128;k++) s += lb[k]*Wl[k*128+t];       s += bl[t];     }
      else if (t < 256) { int h=t-128; for (int k=0;k<128;k++) s += rb[k]*Wr[k*128+h]; s += br[h]; }
      else              { s = bg[t-256]; }
      bcat[t] = s;
    }
  } else {
    if (t < 128) {
      float s = 0.f;
      for (int k=0;k<128;k++) s += Wg[k*128+t];
      sg[t] = s;
    }
  }
}

#define LDK 136  // u16 stride of staged 128-k rows
#define LDA 72
#define LDW 72

// ---------------- K1: fused LN + three projections, n-split waves, direct stores ----------------
// 1152 blocks. LN once -> At (bf16). Per nb: each wave owns 32 n-cols (distinct
// wcat fragments), all 128 m from LDS. Output stored straight from acc as packed
// 8B stores (m-contiguous). launch_bounds(256,4) pins VGPR<=128 (136 halved occupancy).
__global__ __launch_bounds__(256, 4) void k_projln(const float* __restrict__ pair,
    const u16* __restrict__ wcat, const float* __restrict__ bcat, const float* __restrict__ sg,
    u16* __restrict__ left_t, u16* __restrict__ right_t, u16* __restrict__ gate_t) {
  __shared__ u16 At[128*LDK];   // 34816 B
  __shared__ float mu_s[128];
  __shared__ float irs_s[128];
  int bx = blockIdx.x;
  int r0 = bx * 128;
  int t = threadIdx.x, w = t>>6, lane = t&63;
  int q = lane>>4, nl = lane&15;

  // ---- LN phase: 2 threads per row (executed ONCE) ----
  {
    int rr = t >> 1, half = t & 1;
    const float4* gp = (const float4*)(pair + (size_t)(r0+rr)*128 + half*64);
    float4 v[16];
    #pragma unroll
    for (int i=0;i<16;i++) v[i] = gp[i];
    float s=0.f, qq=0.f;
    #pragma unroll
    for (int i=0;i<16;i++) {
      s  += v[i].x + v[i].y + v[i].z + v[i].w;
      qq += v[i].x*v[i].x + v[i].y*v[i].y + v[i].z*v[i].z + v[i].w*v[i].w;
    }
    s  += __shfl_xor(s, 1, 64);
    qq += __shfl_xor(qq, 1, 64);
    float mu = s * (1.f/128.f);
    float var = qq*(1.f/128.f) - mu*mu;
    float rstd = rsqrtf(var + 1e-5f);
    if (half == 0) { mu_s[rr] = mu; irs_s[rr] = 1.0f/rstd; }
    u32* lp = (u32*)(At + rr*LDK + half*64);
    #pragma unroll
    for (int i=0;i<8;i++) {
      u32 p0 = (u32)f2bf((v[2*i].x-mu)*rstd)   | ((u32)f2bf((v[2*i].y-mu)*rstd)<<16);
      u32 p1 = (u32)f2bf((v[2*i].z-mu)*rstd)   | ((u32)f2bf((v[2*i].w-mu)*rstd)<<16);
      u32 p2 = (u32)f2bf((v[2*i+1].x-mu)*rstd) | ((u32)f2bf((v[2*i+1].y-mu)*rstd)<<16);
      u32 p3 = (u32)f2bf((v[2*i+1].z-mu)*rstd) | ((u32)f2bf((v[2*i+1].w-mu)*rstd)<<16);
      ((uint4*)lp)[i] = make_uint4(p0,p1,p2,p3);
    }
  }
  __syncthreads();

  #pragma unroll 1
  for (int nb = 0; nb < 3; ++nb) {
    const u16* bbase = wcat + (size_t)(nb*128)*128;
    f32x4_t acc[8][2] = {};   // [tm][tn] ; m = tm*16+q*4+p, n = w*32+tn*16+nl
    #pragma unroll
    for (int ks=0; ks<4; ks++) {
      int kel = ks*32 + q*8;
      bf16x8_t b0 = *(const bf16x8_t*)(bbase + (size_t)(w*32      + nl)*128 + kel);
      bf16x8_t b1 = *(const bf16x8_t*)(bbase + (size_t)(w*32 + 16 + nl)*128 + kel);
      #pragma unroll
      for (int tm=0;tm<8;tm++) {
        bf16x8_t a = *(const bf16x8_t*)(At + (tm*16+nl)*LDK + kel);
        acc[tm][0] = __builtin_amdgcn_mfma_f32_16x16x32_bf16(a, b0, acc[tm][0], 0,0,0);
        acc[tm][1] = __builtin_amdgcn_mfma_f32_16x16x32_bf16(a, b1, acc[tm][1], 0,0,0);
      }
    }
    u16* dst = (nb==0) ? left_t : (nb==1) ? right_t : gate_t;
    #pragma unroll
    for (int tn=0;tn<2;tn++) {
      int n = w*32 + tn*16 + nl;
      float bias = bcat[nb*128 + n];
      u16* rowp = dst + (size_t)n*M_ + r0;
      if (nb == 2) {
        float sgn = sg[n];
        #pragma unroll
        for (int tm=0;tm<8;tm++) {
          f32x4_t mu4 = *(const f32x4_t*)(mu_s  + tm*16 + q*4);
          f32x4_t ir4 = *(const f32x4_t*)(irs_s + tm*16 + q*4);
          u32 pk0, pk1;
          {
            float v0 = acc[tm][tn][0]*ir4[0] + mu4[0]*sgn + bias;
            float v1 = acc[tm][tn][1]*ir4[1] + mu4[1]*sgn + bias;
            float v2 = acc[tm][tn][2]*ir4[2] + mu4[2]*sgn + bias;
            float v3 = acc[tm][tn][3]*ir4[3] + mu4[3]*sgn + bias;
            v0 = 1.0f/(1.0f+__expf(-v0));
            v1 = 1.0f/(1.0f+__expf(-v1));
            v2 = 1.0f/(1.0f+__expf(-v2));
            v3 = 1.0f/(1.0f+__expf(-v3));
            pk0 = (u32)f2bf(v0) | ((u32)f2bf(v1)<<16);
            pk1 = (u32)f2bf(v2) | ((u32)f2bf(v3)<<16);
          }
          *(u64*)(rowp + tm*16 + q*4) = (u64)pk0 | ((u64)pk1<<32);
        }
      } else {
        #pragma unroll
        for (int tm=0;tm<8;tm++) {
          u32 pk0 = (u32)f2bf(acc[tm][tn][0]+bias) | ((u32)f2bf(acc[tm][tn][1]+bias)<<16);
          u32 pk1 = (u32)f2bf(acc[tm][tn][2]+bias) | ((u32)f2bf(acc[tm][tn][3]+bias)<<16);
          *(u64*)(rowp + tm*16 + q*4) = (u64)pk0 | ((u64)pk1<<32);
        }
      }
    }
  }
}

// ---------------- K2: triangle einsum per h + gate multiply ----------------
// XCD-chunked work remap: all 9 blocks of one h land on the same XCD so the
// 590KB h-group working set stays L2-resident (1152 = 8 XCD x 144, bijective).
__global__ __launch_bounds__(256, 4) void k_einsum(const u16* __restrict__ left_t, const u16* __restrict__ right_t,
    const u16* __restrict__ gate_t, u16* __restrict__ og_t) {
  __shared__ u16 smem[2*128*LDA];  // 36864 B
  u16* At = smem; u16* Bt = smem + 128*LDA;
  int bx = blockIdx.x;
  int wk = (bx & 7) * 144 + (bx >> 3);   // XCD-chunked bijection on 1152
  int h = wk / 9; int rem = wk % 9;
  int i0 = (rem/3)*128, j0 = (rem%3)*128;
  const u16* Ag = left_t + (size_t)h*M_;
  const u16* Bg = right_t + (size_t)h*M_;
  int t = threadIdx.x, w = t>>6, lane = t&63;
  int q = lane>>4, nl = lane&15;
  f32x4_t acc[4][4] = {};
  int m0 = (w&1)*64, n0 = (w>>1)*64;
  for (int kb = 0; kb < N_; kb += 64) {
    { // stage A: left_t rows (i), k contiguous — direct vector copy
      int rr = t>>1, half = t&1;
      const u16* gp = Ag + (size_t)(i0+rr)*N_ + kb + half*32;
      u16* lp = At + rr*LDA + half*32;
      #pragma unroll
      for (int i=0;i<4;i++) ((uint4*)lp)[i] = ((const uint4*)gp)[i];
    }
    { // stage B: register pair-transpose right_t[(kb+k)][j0+j] -> Bt[j][k] (swizzled)
      int kk2 = t>>3;          // 0..31 : k-pair
      int seg = t&7;           // j-chunk of 16
      const u16* g0 = Bg + (size_t)(kb + 2*kk2)*N_ + j0 + seg*16;
      const u16* g1 = g0 + N_;
      uint4 r0a = ((const uint4*)g0)[0], r0b = ((const uint4*)g0)[1];
      uint4 r1a = ((const uint4*)g1)[0], r1b = ((const uint4*)g1)[1];
      u32 w0[8] = {r0a.x,r0a.y,r0a.z,r0a.w,r0b.x,r0b.y,r0b.z,r0b.w};
      u32 w1[8] = {r1a.x,r1a.y,r1a.z,r1a.w,r1b.x,r1b.y,r1b.z,r1b.w};
      u32 sw = (u32)seg << 4;                 // j>>4 == seg for all j in chunk
      char* bbytes = (char*)Bt;
      #pragma unroll
      for (int e=0;e<8;e++) {
        u32 lo = w0[e], hi = w1[e];
        u32 evenw = (lo & 0xffffu) | (hi << 16);
        u32 oddw  = (lo >> 16)     | (hi & 0xffff0000u);
        int je = seg*16 + 2*e;
        u32 byteE = ((u32)(je*LDA + 2*kk2) * 2u) ^ sw;
        u32 byteO = ((u32)((je+1)*LDA + 2*kk2) * 2u) ^ sw;
        *(u32*)(bbytes + byteE) = evenw;
        *(u32*)(bbytes + byteO) = oddw;
      }
    }
    __syncthreads();
    for (int ks=0; ks<2; ks++) {
      int kel = ks*32 + q*8;
      bf16x8_t a[4], b[4];
      #pragma unroll
      for (int tm=0;tm<4;tm++) a[tm] = *(const bf16x8_t*)(At + (m0+tm*16+nl)*LDA + kel);
      #pragma unroll
      for (int tn=0;tn<4;tn++) {
        u32 swr = (u32)(((n0>>4) + tn) & 7) << 4;
        b[tn] = *(const bf16x8_t*)((const char*)Bt + ((u32)(((n0+tn*16+nl)*LDA + kel)*2) ^ swr));
      }
      #pragma unroll
      for (int tm=0;tm<4;tm++)
        #pragma unroll
        for (int tn=0;tn<4;tn++)
          acc[tm][tn] = __builtin_amdgcn_mfma_f32_16x16x32_bf16(a[tm], b[tn], acc[tm][tn], 0,0,0);
    }
    __syncthreads();
  }
  // epilogue: acc -> LDS bf16 [m][n], then gate-multiplied coalesced store (og_t[h][r])
#define LDT 136
  u16* Ot = smem;  // 128*LDT u16 = 34816 B <= 36864
  #pragma unroll
  for (int tm=0;tm<4;tm++)
    #pragma unroll
    for (int tn=0;tn<4;tn++)
      #pragma unroll
      for (int p=0;p<4;p++) {
        int m = m0 + tm*16 + q*4 + p;
        int n = n0 + tn*16 + nl;
        Ot[m*LDT + n] = f2bf(acc[tm][tn][p]);
      }
  __syncthreads();
  {
    int m = t>>1, half = t&1;
    size_t rbase = (size_t)h*M_ + (size_t)(i0+m)*N_ + j0 + half*64;
    const uint4* gg = (const uint4*)(gate_t + rbase);
    const uint4* lo = (const uint4*)(Ot + m*LDT + half*64);
    uint4* od = (uint4*)(og_t + rbase);
    #pragma unroll
    for (int i=0;i<8;i++) {
      uint4 gv = gg[i]; uint4 ov = lo[i];
      u32 ga[4] = {gv.x,gv.y,gv.z,gv.w};
      u32 oa[4] = {ov.x,ov.y,ov.z,ov.w};
      u32 ra[4];
      #pragma unroll
      for (int e=0;e<4;e++) {
        float g0 = bf2f((u16)(ga[e]&0xffffu)), g1 = bf2f((u16)(ga[e]>>16));
        float o0 = bf2f((u16)(oa[e]&0xffffu)), o1 = bf2f((u16)(oa[e]>>16));
        ra[e] = (u32)f2bf(o0*g0) | ((u32)f2bf(o1*g1)<<16);
      }
      od[i] = make_uint4(ra[0],ra[1],ra[2],ra[3]);
    }
  }
}

// ---------------- K3: og @ Wo + bo + pair, rowwise LN, fp32 out ----------------
// A staged from og_t[h][r] with in-LDS transpose (no separate transpose kernel).
__global__ __launch_bounds__(256, 4) void k_final(const u16* __restrict__ og_t, const u16* __restrict__ wot,
    const float* __restrict__ pair, const float* __restrict__ bo,
    const float* __restrict__ ng, const float* __restrict__ nb_,
    float* __restrict__ out) {
  __shared__ u16 smem[2*128*LDW];  // 36864 B
  u16* At = smem; u16* Wt = smem + 128*LDW;
  int bx = blockIdx.x;
  int r0 = bx * 128;
  int t = threadIdx.x, w = t>>6, lane = t&63;
  int q = lane>>4, nl = lane&15;
  f32x4_t acc[2][8] = {};
  for (int c0 = 0; c0 < 128; c0 += 64) {
    { // stage A with transpose: og_t[(c0+hh)*M + r0+r] -> At[r][hh]
      int hh = t>>2, seg = t&3;
      const u16* gp = og_t + (size_t)(c0+hh)*M_ + r0 + seg*32;
      uint4 bb[4];
      #pragma unroll
      for (int i=0;i<4;i++) bb[i] = ((const uint4*)gp)[i];
      #pragma unroll
      for (int i=0;i<4;i++) {
        int rb = seg*32 + i*8;
        u32 x0=bb[i].x, x1=bb[i].y, x2=bb[i].z, x3=bb[i].w;
        At[(rb+0)*LDW+hh] = (u16)(x0&0xffffu); At[(rb+1)*LDW+hh] = (u16)(x0>>16);
        At[(rb+2)*LDW+hh] = (u16)(x1&0xffffu); At[(rb+3)*LDW+hh] = (u16)(x1>>16);
        At[(rb+4)*LDW+hh] = (u16)(x2&0xffffu); At[(rb+5)*LDW+hh] = (u16)(x2>>16);
        At[(rb+6)*LDW+hh] = (u16)(x3&0xffffu); At[(rb+7)*LDW+hh] = (u16)(x3>>16);
      }
    }
    { // stage Wo chunk: Wt[c][h']
      int c = t>>1, half = t&1;
      const u16* gp = wot + (size_t)c*128 + c0 + half*32;
      u16* lp = Wt + c*LDW + half*32;
      #pragma unroll
      for (int i=0;i<4;i++) ((uint4*)lp)[i] = ((const uint4*)gp)[i];
    }
    __syncthreads();
    int mbase = w*32;
    for (int ks=0; ks<2; ks++) {
      int kel = ks*32 + q*8;
      bf16x8_t a[2], b[8];
      #pragma unroll
      for (int tm=0;tm<2;tm++) a[tm] = *(const bf16x8_t*)(At + (mbase+tm*16+nl)*LDW + kel);
      #pragma unroll
      for (int tn=0;tn<8;tn++) b[tn] = *(const bf16x8_t*)(Wt + (tn*16+nl)*LDW + kel);
      #pragma unroll
      for (int tm=0;tm<2;tm++)
        #pragma unroll
        for (int tn=0;tn<8;tn++)
          acc[tm][tn] = __builtin_amdgcn_mfma_f32_16x16x32_bf16(a[tm], b[tn], acc[tm][tn], 0,0,0);
    }
    __syncthreads();
  }
  // epilogue: residual + bias, transpose-free rowwise LN via 16-lane shfl reduction
  float rsum[2][4], rsq[2][4];
  for (int tm=0;tm<2;tm++) for (int p=0;p<4;p++) { rsum[tm][p]=0.f; rsq[tm][p]=0.f; }
  #pragma unroll
  for (int tm=0;tm<2;tm++)
    #pragma unroll
    for (int tn=0;tn<8;tn++) {
      int n = tn*16 + nl;
      float bb = bo[n];
      #pragma unroll
      for (int p=0;p<4;p++) {
        int m = w*32 + tm*16 + q*4 + p;
        float v = acc[tm][tn][p] + bb + pair[(size_t)(r0+m)*128 + n];
        acc[tm][tn][p] = v;
        rsum[tm][p] += v;
        rsq[tm][p]  += v*v;
      }
    }
  for (int msk=1; msk<16; msk<<=1) {
    #pragma unroll
    for (int tm=0;tm<2;tm++)
      #pragma unroll
      for (int p=0;p<4;p++) {
        rsum[tm][p] += __shfl_xor(rsum[tm][p], msk, 64);
        rsq[tm][p]  += __shfl_xor(rsq[tm][p],  msk, 64);
      }
  }
  #pragma unroll
  for (int tm=0;tm<2;tm++)
    #pragma unroll
    for (int p=0;p<4;p++) {
      float mu = rsum[tm][p] * (1.f/128.f);
      float var = rsq[tm][p]*(1.f/128.f) - mu*mu;
      rsum[tm][p] = mu;
      rsq[tm][p] = rsqrtf(var + 1e-5f);
    }
  #pragma unroll
  for (int tm=0;tm<2;tm++)
    #pragma unroll
    for (int tn=0;tn<8;tn++) {
      int n = tn*16 + nl;
      float g = ng[n], b2 = nb_[n];
      #pragma unroll
      for (int p=0;p<4;p++) {
        int m = w*32 + tm*16 + q*4 + p;
        out[(size_t)(r0+m)*128 + n] = (acc[tm][tn][p] - rsum[tm][p]) * rsq[tm][p] * g + b2;
      }
    }
}

extern "C" void kernel_launch(void* const* d_in, const int* in_sizes, int n_in,
                              void* d_out, int out_size, void* d_ws, size_t ws_size,
                              hipStream_t stream) {
  (void)in_sizes; (void)n_in; (void)out_size; (void)ws_size;
  const float* pair   = (const float*)d_in[0];
  const float* ln_l_g = (const float*)d_in[1];
  const float* ln_l_b = (const float*)d_in[2];
  const float* ln_r_g = (const float*)d_in[3];
  const float* ln_r_b = (const float*)d_in[4];
  const float* Wl = (const float*)d_in[5];
  const float* bl = (const float*)d_in[6];
  const float* Wr = (const float*)d_in[7];
  const float* br = (const float*)d_in[8];
  const float* Wg = (const float*)d_in[9];
  const float* bg = (const float*)d_in[10];
  const float* Wo = (const float*)d_in[11];
  const float* bo = (const float*)d_in[12];
  const float* n_g = (const float*)d_in[13];
  const float* n_b = (const float*)d_in[14];

  char* ws = (char*)d_ws;
  const size_t SZ = (size_t)M_*128*sizeof(u16);         // 37,748,736 B
  u16*  og_t    = (u16*)(ws);                           // written by k_einsum
  u16*  gate_t  = (u16*)(ws + SZ);
  u16*  wcat    = (u16*)(ws + 2*SZ);
  float* bcat   = (float*)(ws + 2*SZ + 98304);
  float* sgp    = (float*)(ws + 2*SZ + 98304 + 1536);
  u16*  wot     = (u16*)(ws + 2*SZ + 98304 + 1536 + 512);

  // left_t / right_t live in d_out until k_final overwrites it with the result
  u16* left_t   = (u16*)d_out;
  u16* right_t  = (u16*)d_out + (size_t)M_*128;

  k_prep1<<<256, 256, 0, stream>>>(ln_l_g, ln_r_g, Wl, Wr, Wg, Wo, wcat, wot);
  k_prep2<<<2, 512, 0, stream>>>(ln_l_b, ln_r_b, Wl, Wr, Wg, bl, br, bg, bcat, sgp);
  k_projln<<<1152, 256, 0, stream>>>(pair, wcat, bcat, sgp, left_t, right_t, gate_t);
  k_einsum<<<1152, 256, 0, stream>>>(left_t, right_t, gate_t, og_t);
  k_final<<<1152, 256, 0, stream>>>(og_t, wot, pair, bo, n_g, n_b, (float*)d_out);
}

// Round 4
// 279.449 us; speedup vs baseline: 1.5227x; 1.5227x over previous
//
#include <hip/hip_runtime.h>
#include <hip/hip_bf16.h>

#define N_ 384
#define C_ 128
#define M_ (N_*N_)   // 147456 rows (i*384+j)

typedef __attribute__((ext_vector_type(8))) short bf16x8_t;
typedef __attribute__((ext_vector_type(4))) float f32x4_t;
typedef unsigned int u32;
typedef unsigned short u16;
typedef unsigned long long u64;

__device__ __forceinline__ u16 f2bf(float f) {
  u32 u = __builtin_bit_cast(u32, f);
  u32 r = (u + 0x7FFFu + ((u >> 16) & 1u)) >> 16;
  return (u16)r;
}
__device__ __forceinline__ float bf2f(u16 h) {
  u32 u = ((u32)h) << 16;
  return __builtin_bit_cast(float, u);
}

// ---------------- prep kernels ----------------
__global__ __launch_bounds__(256) void k_prep1(const float* __restrict__ lg, const float* __restrict__ rg,
    const float* __restrict__ Wl, const float* __restrict__ Wr, const float* __restrict__ Wg,
    const float* __restrict__ Wo, u16* __restrict__ wcat, u16* __restrict__ wot) {
  int idx = blockIdx.x*256 + threadIdx.x;
  if (idx < 49152) {
    int n = idx >> 7, k = idx & 127;
    float v;
    if (n < 128)      v = lg[k] * Wl[k*128 + n];
    else if (n < 256) v = rg[k] * Wr[k*128 + (n-128)];
    else              v = Wg[k*128 + (n-256)];
    wcat[idx] = f2bf(v);
  } else {
    int i2 = idx - 49152;           // < 16384
    int c = i2 >> 7, h = i2 & 127;
    wot[i2] = f2bf(Wo[h*128 + c]);
  }
}

__global__ __launch_bounds__(512) void k_prep2(const float* __restrict__ lb, const float* __restrict__ rb,
    const float* __restrict__ Wl, const float* __restrict__ Wr, const float* __restrict__ Wg,
    const float* __restrict__ bl, const float* __restrict__ br, const float* __restrict__ bg,
    float* __restrict__ bcat, float* __restrict__ sg) {
  int t = threadIdx.x;
  if (blockIdx.x == 0) {
    if (t < 384) {
      float s = 0.f;
      if (t < 128)      { for (int k=0;k<128;k++) s += lb[k]*Wl[k*128+t];       s += bl[t];     }
      else if (t < 256) { int h=t-128; for (int k=0;k<128;k++) s += rb[k]*Wr[k*128+h]; s += br[h]; }
      else              { s = bg[t-256]; }
      bcat[t] = s;
    }
  } else {
    if (t < 128) {
      float s = 0.f;
      for (int k=0;k<128;k++) s += Wg[k*128+t];
      sg[t] = s;
    }
  }
}

#define LDK 136  // u16 stride of staged 128-k rows
#define LDA 72
#define LDW 72

// ---------------- K1: fused LN + three projections, 512 threads, 16 n-cols/wave ----------------
// 1152 blocks x 512 threads (8 waves). LN once -> At (bf16), 4 threads/row.
// Per nb: each wave owns 16 n-cols -> acc is only 8 f32x4 (32 VGPR), no spill,
// natural VGPR ~<100 -> ~5 waves/SIMD. Direct packed 8B stores, no epilogue barriers.
__global__ __launch_bounds__(512) void k_projln(const float* __restrict__ pair,
    const u16* __restrict__ wcat, const float* __restrict__ bcat, const float* __restrict__ sg,
    u16* __restrict__ left_t, u16* __restrict__ right_t, u16* __restrict__ gate_t) {
  __shared__ u16 At[128*LDK];   // 34816 B
  __shared__ float mu_s[128];
  __shared__ float irs_s[128];
  int bx = blockIdx.x;
  int r0 = bx * 128;
  int t = threadIdx.x, w = t>>6, lane = t&63;
  int q = lane>>4, nl = lane&15;

  // ---- LN phase: 4 threads per row (executed ONCE) ----
  {
    int rr = t >> 2, quarter = t & 3;
    const float4* gp = (const float4*)(pair + (size_t)(r0+rr)*128 + quarter*32);
    float4 v[8];
    #pragma unroll
    for (int i=0;i<8;i++) v[i] = gp[i];
    float s=0.f, qq=0.f;
    #pragma unroll
    for (int i=0;i<8;i++) {
      s  += v[i].x + v[i].y + v[i].z + v[i].w;
      qq += v[i].x*v[i].x + v[i].y*v[i].y + v[i].z*v[i].z + v[i].w*v[i].w;
    }
    s  += __shfl_xor(s, 1, 64);
    s  += __shfl_xor(s, 2, 64);
    qq += __shfl_xor(qq, 1, 64);
    qq += __shfl_xor(qq, 2, 64);
    float mu = s * (1.f/128.f);
    float var = qq*(1.f/128.f) - mu*mu;
    float rstd = rsqrtf(var + 1e-5f);
    if (quarter == 0) { mu_s[rr] = mu; irs_s[rr] = 1.0f/rstd; }
    u32* lp = (u32*)(At + rr*LDK + quarter*32);
    #pragma unroll
    for (int i=0;i<4;i++) {
      u32 p0 = (u32)f2bf((v[2*i].x-mu)*rstd)   | ((u32)f2bf((v[2*i].y-mu)*rstd)<<16);
      u32 p1 = (u32)f2bf((v[2*i].z-mu)*rstd)   | ((u32)f2bf((v[2*i].w-mu)*rstd)<<16);
      u32 p2 = (u32)f2bf((v[2*i+1].x-mu)*rstd) | ((u32)f2bf((v[2*i+1].y-mu)*rstd)<<16);
      u32 p3 = (u32)f2bf((v[2*i+1].z-mu)*rstd) | ((u32)f2bf((v[2*i+1].w-mu)*rstd)<<16);
      ((uint4*)lp)[i] = make_uint4(p0,p1,p2,p3);
    }
  }
  __syncthreads();

  #pragma unroll 1
  for (int nb = 0; nb < 3; ++nb) {
    const u16* bbase = wcat + (size_t)(nb*128)*128;
    f32x4_t acc[8] = {};   // [tm] ; m = tm*16+q*4+p, n = w*16+nl
    #pragma unroll
    for (int ks=0; ks<4; ks++) {
      int kel = ks*32 + q*8;
      bf16x8_t b = *(const bf16x8_t*)(bbase + (size_t)(w*16 + nl)*128 + kel);
      #pragma unroll
      for (int tm=0;tm<8;tm++) {
        bf16x8_t a = *(const bf16x8_t*)(At + (tm*16+nl)*LDK + kel);
        acc[tm] = __builtin_amdgcn_mfma_f32_16x16x32_bf16(a, b, acc[tm], 0,0,0);
      }
    }
    u16* dst = (nb==0) ? left_t : (nb==1) ? right_t : gate_t;
    int n = w*16 + nl;
    float bias = bcat[nb*128 + n];
    u16* rowp = dst + (size_t)n*M_ + r0;
    if (nb == 2) {
      float sgn = sg[n];
      #pragma unroll
      for (int tm=0;tm<8;tm++) {
        f32x4_t mu4 = *(const f32x4_t*)(mu_s  + tm*16 + q*4);
        f32x4_t ir4 = *(const f32x4_t*)(irs_s + tm*16 + q*4);
        float v0 = acc[tm][0]*ir4[0] + mu4[0]*sgn + bias;
        float v1 = acc[tm][1]*ir4[1] + mu4[1]*sgn + bias;
        float v2 = acc[tm][2]*ir4[2] + mu4[2]*sgn + bias;
        float v3 = acc[tm][3]*ir4[3] + mu4[3]*sgn + bias;
        v0 = 1.0f/(1.0f+__expf(-v0));
        v1 = 1.0f/(1.0f+__expf(-v1));
        v2 = 1.0f/(1.0f+__expf(-v2));
        v3 = 1.0f/(1.0f+__expf(-v3));
        u32 pk0 = (u32)f2bf(v0) | ((u32)f2bf(v1)<<16);
        u32 pk1 = (u32)f2bf(v2) | ((u32)f2bf(v3)<<16);
        *(u64*)(rowp + tm*16 + q*4) = (u64)pk0 | ((u64)pk1<<32);
      }
    } else {
      #pragma unroll
      for (int tm=0;tm<8;tm++) {
        u32 pk0 = (u32)f2bf(acc[tm][0]+bias) | ((u32)f2bf(acc[tm][1]+bias)<<16);
        u32 pk1 = (u32)f2bf(acc[tm][2]+bias) | ((u32)f2bf(acc[tm][3]+bias)<<16);
        *(u64*)(rowp + tm*16 + q*4) = (u64)pk0 | ((u64)pk1<<32);
      }
    }
  }
}

// ---------------- K2: triangle einsum per h + gate multiply ----------------
// XCD-chunked work remap: all 9 blocks of one h land on the same XCD so the
// 590KB h-group working set stays L2-resident (1152 = 8 XCD x 144, bijective).
__global__ __launch_bounds__(256) void k_einsum(const u16* __restrict__ left_t, const u16* __restrict__ right_t,
    const u16* __restrict__ gate_t, u16* __restrict__ og_t) {
  __shared__ u16 smem[2*128*LDA];  // 36864 B
  u16* At = smem; u16* Bt = smem + 128*LDA;
  int bx = blockIdx.x;
  int wk = (bx & 7) * 144 + (bx >> 3);   // XCD-chunked bijection on 1152
  int h = wk / 9; int rem = wk % 9;
  int i0 = (rem/3)*128, j0 = (rem%3)*128;
  const u16* Ag = left_t + (size_t)h*M_;
  const u16* Bg = right_t + (size_t)h*M_;
  int t = threadIdx.x, w = t>>6, lane = t&63;
  int q = lane>>4, nl = lane&15;
  f32x4_t acc[4][4] = {};
  int m0 = (w&1)*64, n0 = (w>>1)*64;
  for (int kb = 0; kb < N_; kb += 64) {
    { // stage A: left_t rows (i), k contiguous — direct vector copy
      int rr = t>>1, half = t&1;
      const u16* gp = Ag + (size_t)(i0+rr)*N_ + kb + half*32;
      u16* lp = At + rr*LDA + half*32;
      #pragma unroll
      for (int i=0;i<4;i++) ((uint4*)lp)[i] = ((const uint4*)gp)[i];
    }
    { // stage B: register pair-transpose right_t[(kb+k)][j0+j] -> Bt[j][k] (swizzled)
      int kk2 = t>>3;          // 0..31 : k-pair
      int seg = t&7;           // j-chunk of 16
      const u16* g0 = Bg + (size_t)(kb + 2*kk2)*N_ + j0 + seg*16;
      const u16* g1 = g0 + N_;
      uint4 r0a = ((const uint4*)g0)[0], r0b = ((const uint4*)g0)[1];
      uint4 r1a = ((const uint4*)g1)[0], r1b = ((const uint4*)g1)[1];
      u32 w0[8] = {r0a.x,r0a.y,r0a.z,r0a.w,r0b.x,r0b.y,r0b.z,r0b.w};
      u32 w1[8] = {r1a.x,r1a.y,r1a.z,r1a.w,r1b.x,r1b.y,r1b.z,r1b.w};
      u32 sw = (u32)seg << 4;                 // j>>4 == seg for all j in chunk
      char* bbytes = (char*)Bt;
      #pragma unroll
      for (int e=0;e<8;e++) {
        u32 lo = w0[e], hi = w1[e];
        u32 evenw = (lo & 0xffffu) | (hi << 16);
        u32 oddw  = (lo >> 16)     | (hi & 0xffff0000u);
        int je = seg*16 + 2*e;
        u32 byteE = ((u32)(je*LDA + 2*kk2) * 2u) ^ sw;
        u32 byteO = ((u32)((je+1)*LDA + 2*kk2) * 2u) ^ sw;
        *(u32*)(bbytes + byteE) = evenw;
        *(u32*)(bbytes + byteO) = oddw;
      }
    }
    __syncthreads();
    for (int ks=0; ks<2; ks++) {
      int kel = ks*32 + q*8;
      bf16x8_t a[4], b[4];
      #pragma unroll
      for (int tm=0;tm<4;tm++) a[tm] = *(const bf16x8_t*)(At + (m0+tm*16+nl)*LDA + kel);
      #pragma unroll
      for (int tn=0;tn<4;tn++) {
        u32 swr = (u32)(((n0>>4) + tn) & 7) << 4;
        b[tn] = *(const bf16x8_t*)((const char*)Bt + ((u32)(((n0+tn*16+nl)*LDA + kel)*2) ^ swr));
      }
      #pragma unroll
      for (int tm=0;tm<4;tm++)
        #pragma unroll
        for (int tn=0;tn<4;tn++)
          acc[tm][tn] = __builtin_amdgcn_mfma_f32_16x16x32_bf16(a[tm], b[tn], acc[tm][tn], 0,0,0);
    }
    __syncthreads();
  }
  // epilogue: acc -> LDS bf16 [m][n], then gate-multiplied coalesced store (og_t[h][r])
#define LDT 136
  u16* Ot = smem;  // 128*LDT u16 = 34816 B <= 36864
  #pragma unroll
  for (int tm=0;tm<4;tm++)
    #pragma unroll
    for (int tn=0;tn<4;tn++)
      #pragma unroll
      for (int p=0;p<4;p++) {
        int m = m0 + tm*16 + q*4 + p;
        int n = n0 + tn*16 + nl;
        Ot[m*LDT + n] = f2bf(acc[tm][tn][p]);
      }
  __syncthreads();
  {
    int m = t>>1, half = t&1;
    size_t rbase = (size_t)h*M_ + (size_t)(i0+m)*N_ + j0 + half*64;
    const uint4* gg = (const uint4*)(gate_t + rbase);
    const uint4* lo = (const uint4*)(Ot + m*LDT + half*64);
    uint4* od = (uint4*)(og_t + rbase);
    #pragma unroll
    for (int i=0;i<8;i++) {
      uint4 gv = gg[i]; uint4 ov = lo[i];
      u32 ga[4] = {gv.x,gv.y,gv.z,gv.w};
      u32 oa[4] = {ov.x,ov.y,ov.z,ov.w};
      u32 ra[4];
      #pragma unroll
      for (int e=0;e<4;e++) {
        float g0 = bf2f((u16)(ga[e]&0xffffu)), g1 = bf2f((u16)(ga[e]>>16));
        float o0 = bf2f((u16)(oa[e]&0xffffu)), o1 = bf2f((u16)(oa[e]>>16));
        ra[e] = (u32)f2bf(o0*g0) | ((u32)f2bf(o1*g1)<<16);
      }
      od[i] = make_uint4(ra[0],ra[1],ra[2],ra[3]);
    }
  }
}

// ---------------- K3: og @ Wo + bo + pair, rowwise LN, fp32 out ----------------
// A staged from og_t[h][r] with in-LDS transpose (no separate transpose kernel).
__global__ __launch_bounds__(256) void k_final(const u16* __restrict__ og_t, const u16* __restrict__ wot,
    const float* __restrict__ pair, const float* __restrict__ bo,
    const float* __restrict__ ng, const float* __restrict__ nb_,
    float* __restrict__ out) {
  __shared__ u16 smem[2*128*LDW];  // 36864 B
  u16* At = smem; u16* Wt = smem + 128*LDW;
  int bx = blockIdx.x;
  int r0 = bx * 128;
  int t = threadIdx.x, w = t>>6, lane = t&63;
  int q = lane>>4, nl = lane&15;
  f32x4_t acc[2][8] = {};
  for (int c0 = 0; c0 < 128; c0 += 64) {
    { // stage A with transpose: og_t[(c0+hh)*M + r0+r] -> At[r][hh]
      int hh = t>>2, seg = t&3;
      const u16* gp = og_t + (size_t)(c0+hh)*M_ + r0 + seg*32;
      uint4 bb[4];
      #pragma unroll
      for (int i=0;i<4;i++) bb[i] = ((const uint4*)gp)[i];
      #pragma unroll
      for (int i=0;i<4;i++) {
        int rb = seg*32 + i*8;
        u32 x0=bb[i].x, x1=bb[i].y, x2=bb[i].z, x3=bb[i].w;
        At[(rb+0)*LDW+hh] = (u16)(x0&0xffffu); At[(rb+1)*LDW+hh] = (u16)(x0>>16);
        At[(rb+2)*LDW+hh] = (u16)(x1&0xffffu); At[(rb+3)*LDW+hh] = (u16)(x1>>16);
        At[(rb+4)*LDW+hh] = (u16)(x2&0xffffu); At[(rb+5)*LDW+hh] = (u16)(x2>>16);
        At[(rb+6)*LDW+hh] = (u16)(x3&0xffffu); At[(rb+7)*LDW+hh] = (u16)(x3>>16);
      }
    }
    { // stage Wo chunk: Wt[c][h']
      int c = t>>1, half = t&1;
      const u16* gp = wot + (size_t)c*128 + c0 + half*32;
      u16* lp = Wt + c*LDW + half*32;
      #pragma unroll
      for (int i=0;i<4;i++) ((uint4*)lp)[i] = ((const uint4*)gp)[i];
    }
    __syncthreads();
    int mbase = w*32;
    for (int ks=0; ks<2; ks++) {
      int kel = ks*32 + q*8;
      bf16x8_t a[2], b[8];
      #pragma unroll
      for (int tm=0;tm<2;tm++) a[tm] = *(const bf16x8_t*)(At + (mbase+tm*16+nl)*LDW + kel);
      #pragma unroll
      for (int tn=0;tn<8;tn++) b[tn] = *(const bf16x8_t*)(Wt + (tn*16+nl)*LDW + kel);
      #pragma unroll
      for (int tm=0;tm<2;tm++)
        #pragma unroll
        for (int tn=0;tn<8;tn++)
          acc[tm][tn] = __builtin_amdgcn_mfma_f32_16x16x32_bf16(a[tm], b[tn], acc[tm][tn], 0,0,0);
    }
    __syncthreads();
  }
  // epilogue: residual + bias, transpose-free rowwise LN via 16-lane shfl reduction
  float rsum[2][4], rsq[2][4];
  for (int tm=0;tm<2;tm++) for (int p=0;p<4;p++) { rsum[tm][p]=0.f; rsq[tm][p]=0.f; }
  #pragma unroll
  for (int tm=0;tm<2;tm++)
    #pragma unroll
    for (int tn=0;tn<8;tn++) {
      int n = tn*16 + nl;
      float bb = bo[n];
      #pragma unroll
      for (int p=0;p<4;p++) {
        int m = w*32 + tm*16 + q*4 + p;
        float v = acc[tm][tn][p] + bb + pair[(size_t)(r0+m)*128 + n];
        acc[tm][tn][p] = v;
        rsum[tm][p] += v;
        rsq[tm][p]  += v*v;
      }
    }
  for (int msk=1; msk<16; msk<<=1) {
    #pragma unroll
    for (int tm=0;tm<2;tm++)
      #pragma unroll
      for (int p=0;p<4;p++) {
        rsum[tm][p] += __shfl_xor(rsum[tm][p], msk, 64);
        rsq[tm][p]  += __shfl_xor(rsq[tm][p],  msk, 64);
      }
  }
  #pragma unroll
  for (int tm=0;tm<2;tm++)
    #pragma unroll
    for (int p=0;p<4;p++) {
      float mu = rsum[tm][p] * (1.f/128.f);
      float var = rsq[tm][p]*(1.f/128.f) - mu*mu;
      rsum[tm][p] = mu;
      rsq[tm][p] = rsqrtf(var + 1e-5f);
    }
  #pragma unroll
  for (int tm=0;tm<2;tm++)
    #pragma unroll
    for (int tn=0;tn<8;tn++) {
      int n = tn*16 + nl;
      float g = ng[n], b2 = nb_[n];
      #pragma unroll
      for (int p=0;p<4;p++) {
        int m = w*32 + tm*16 + q*4 + p;
        out[(size_t)(r0+m)*128 + n] = (acc[tm][tn][p] - rsum[tm][p]) * rsq[tm][p] * g + b2;
      }
    }
}

extern "C" void kernel_launch(void* const* d_in, const int* in_sizes, int n_in,
                              void* d_out, int out_size, void* d_ws, size_t ws_size,
                              hipStream_t stream) {
  (void)in_sizes; (void)n_in; (void)out_size; (void)ws_size;
  const float* pair   = (const float*)d_in[0];
  const float* ln_l_g = (const float*)d_in[1];
  const float* ln_l_b = (const float*)d_in[2];
  const float* ln_r_g = (const float*)d_in[3];
  const float* ln_r_b = (const float*)d_in[4];
  const float* Wl = (const float*)d_in[5];
  const float* bl = (const float*)d_in[6];
  const float* Wr = (const float*)d_in[7];
  const float* br = (const float*)d_in[8];
  const float* Wg = (const float*)d_in[9];
  const float* bg = (const float*)d_in[10];
  const float* Wo = (const float*)d_in[11];
  const float* bo = (const float*)d_in[12];
  const float* n_g = (const float*)d_in[13];
  const float* n_b = (const float*)d_in[14];

  char* ws = (char*)d_ws;
  const size_t SZ = (size_t)M_*128*sizeof(u16);         // 37,748,736 B
  u16*  og_t    = (u16*)(ws);                           // written by k_einsum
  u16*  gate_t  = (u16*)(ws + SZ);
  u16*  wcat    = (u16*)(ws + 2*SZ);
  float* bcat   = (float*)(ws + 2*SZ + 98304);
  float* sgp    = (float*)(ws + 2*SZ + 98304 + 1536);
  u16*  wot     = (u16*)(ws + 2*SZ + 98304 + 1536 + 512);

  // left_t / right_t live in d_out until k_final overwrites it with the result
  u16* left_t   = (u16*)d_out;
  u16* right_t  = (u16*)d_out + (size_t)M_*128;

  k_prep1<<<256, 256, 0, stream>>>(ln_l_g, ln_r_g, Wl, Wr, Wg, Wo, wcat, wot);
  k_prep2<<<2, 512, 0, stream>>>(ln_l_b, ln_r_b, Wl, Wr, Wg, bl, br, bg, bcat, sgp);
  k_projln<<<1152, 512, 0, stream>>>(pair, wcat, bcat, sgp, left_t, right_t, gate_t);
  k_einsum<<<1152, 256, 0, stream>>>(left_t, right_t, gate_t, og_t);
  k_final<<<1152, 256, 0, stream>>>(og_t, wot, pair, bo, n_g, n_b, (float*)d_out);
}

// Round 5
// 271.372 us; speedup vs baseline: 1.5680x; 1.0298x over previous
//
#include <hip/hip_runtime.h>
#include <hip/hip_bf16.h>

#define N_ 384
#define C_ 128
#define M_ (N_*N_)   // 147456 rows (i*384+j)

typedef __attribute__((ext_vector_type(8))) short bf16x8_t;
typedef __attribute__((ext_vector_type(4))) float f32x4_t;
typedef unsigned int u32;
typedef unsigned short u16;
typedef unsigned long long u64;

__device__ __forceinline__ u16 f2bf(float f) {
  u32 u = __builtin_bit_cast(u32, f);
  u32 r = (u + 0x7FFFu + ((u >> 16) & 1u)) >> 16;
  return (u16)r;
}
__device__ __forceinline__ float bf2f(u16 h) {
  u32 u = ((u32)h) << 16;
  return __builtin_bit_cast(float, u);
}

// ---------------- fused prep kernel (prep1 + prep2 in one launch) ----------------
__global__ __launch_bounds__(256) void k_prep(const float* __restrict__ lg, const float* __restrict__ rg,
    const float* __restrict__ Wl, const float* __restrict__ Wr, const float* __restrict__ Wg,
    const float* __restrict__ Wo,
    const float* __restrict__ lb, const float* __restrict__ rb,
    const float* __restrict__ bl, const float* __restrict__ br, const float* __restrict__ bg,
    u16* __restrict__ wcat, u16* __restrict__ wot,
    float* __restrict__ bcat, float* __restrict__ sg) {
  int bx = blockIdx.x, t = threadIdx.x;
  if (bx < 256) {
    int idx = bx*256 + t;
    if (idx < 49152) {
      int n = idx >> 7, k = idx & 127;
      float v;
      if (n < 128)      v = lg[k] * Wl[k*128 + n];
      else if (n < 256) v = rg[k] * Wr[k*128 + (n-128)];
      else              v = Wg[k*128 + (n-256)];
      wcat[idx] = f2bf(v);
    } else {
      int i2 = idx - 49152;           // < 16384
      int c = i2 >> 7, h = i2 & 127;
      wot[i2] = f2bf(Wo[h*128 + c]);
    }
  } else if (bx == 256) {
    float s = 0.f;
    if (t < 128)      { for (int k=0;k<128;k++) s += lb[k]*Wl[k*128+t];       s += bl[t];     bcat[t] = s; }
    else              { int hh=t-128; for (int k=0;k<128;k++) s += rb[k]*Wr[k*128+hh]; s += br[hh]; bcat[t] = s; }
  } else {
    if (t < 128)      { bcat[256+t] = bg[t]; }
    else              { int hh = t-128; float s=0.f; for (int k=0;k<128;k++) s += Wg[k*128+hh]; sg[hh] = s; }
  }
}

#define LDK 136  // u16 stride of staged 128-k rows
#define LDA 72
#define LDW 72
#define LDT 136

// ---------------- K1: fused LN + three projections, 512 threads, 16 n-cols/wave ----------------
// (unchanged from round 4 — measured 80us, VGPR=104, serves as noise control)
__global__ __launch_bounds__(512) void k_projln(const float* __restrict__ pair,
    const u16* __restrict__ wcat, const float* __restrict__ bcat, const float* __restrict__ sg,
    u16* __restrict__ left_t, u16* __restrict__ right_t, u16* __restrict__ gate_t) {
  __shared__ u16 At[128*LDK];   // 34816 B
  __shared__ float mu_s[128];
  __shared__ float irs_s[128];
  int bx = blockIdx.x;
  int r0 = bx * 128;
  int t = threadIdx.x, w = t>>6, lane = t&63;
  int q = lane>>4, nl = lane&15;

  // ---- LN phase: 4 threads per row (executed ONCE) ----
  {
    int rr = t >> 2, quarter = t & 3;
    const float4* gp = (const float4*)(pair + (size_t)(r0+rr)*128 + quarter*32);
    float4 v[8];
    #pragma unroll
    for (int i=0;i<8;i++) v[i] = gp[i];
    float s=0.f, qq=0.f;
    #pragma unroll
    for (int i=0;i<8;i++) {
      s  += v[i].x + v[i].y + v[i].z + v[i].w;
      qq += v[i].x*v[i].x + v[i].y*v[i].y + v[i].z*v[i].z + v[i].w*v[i].w;
    }
    s  += __shfl_xor(s, 1, 64);
    s  += __shfl_xor(s, 2, 64);
    qq += __shfl_xor(qq, 1, 64);
    qq += __shfl_xor(qq, 2, 64);
    float mu = s * (1.f/128.f);
    float var = qq*(1.f/128.f) - mu*mu;
    float rstd = rsqrtf(var + 1e-5f);
    if (quarter == 0) { mu_s[rr] = mu; irs_s[rr] = 1.0f/rstd; }
    u32* lp = (u32*)(At + rr*LDK + quarter*32);
    #pragma unroll
    for (int i=0;i<4;i++) {
      u32 p0 = (u32)f2bf((v[2*i].x-mu)*rstd)   | ((u32)f2bf((v[2*i].y-mu)*rstd)<<16);
      u32 p1 = (u32)f2bf((v[2*i].z-mu)*rstd)   | ((u32)f2bf((v[2*i].w-mu)*rstd)<<16);
      u32 p2 = (u32)f2bf((v[2*i+1].x-mu)*rstd) | ((u32)f2bf((v[2*i+1].y-mu)*rstd)<<16);
      u32 p3 = (u32)f2bf((v[2*i+1].z-mu)*rstd) | ((u32)f2bf((v[2*i+1].w-mu)*rstd)<<16);
      ((uint4*)lp)[i] = make_uint4(p0,p1,p2,p3);
    }
  }
  __syncthreads();

  #pragma unroll 1
  for (int nb = 0; nb < 3; ++nb) {
    const u16* bbase = wcat + (size_t)(nb*128)*128;
    f32x4_t acc[8] = {};   // [tm] ; m = tm*16+q*4+p, n = w*16+nl
    #pragma unroll
    for (int ks=0; ks<4; ks++) {
      int kel = ks*32 + q*8;
      bf16x8_t b = *(const bf16x8_t*)(bbase + (size_t)(w*16 + nl)*128 + kel);
      #pragma unroll
      for (int tm=0;tm<8;tm++) {
        bf16x8_t a = *(const bf16x8_t*)(At + (tm*16+nl)*LDK + kel);
        acc[tm] = __builtin_amdgcn_mfma_f32_16x16x32_bf16(a, b, acc[tm], 0,0,0);
      }
    }
    u16* dst = (nb==0) ? left_t : (nb==1) ? right_t : gate_t;
    int n = w*16 + nl;
    float bias = bcat[nb*128 + n];
    u16* rowp = dst + (size_t)n*M_ + r0;
    if (nb == 2) {
      float sgn = sg[n];
      #pragma unroll
      for (int tm=0;tm<8;tm++) {
        f32x4_t mu4 = *(const f32x4_t*)(mu_s  + tm*16 + q*4);
        f32x4_t ir4 = *(const f32x4_t*)(irs_s + tm*16 + q*4);
        float v0 = acc[tm][0]*ir4[0] + mu4[0]*sgn + bias;
        float v1 = acc[tm][1]*ir4[1] + mu4[1]*sgn + bias;
        float v2 = acc[tm][2]*ir4[2] + mu4[2]*sgn + bias;
        float v3 = acc[tm][3]*ir4[3] + mu4[3]*sgn + bias;
        v0 = 1.0f/(1.0f+__expf(-v0));
        v1 = 1.0f/(1.0f+__expf(-v1));
        v2 = 1.0f/(1.0f+__expf(-v2));
        v3 = 1.0f/(1.0f+__expf(-v3));
        u32 pk0 = (u32)f2bf(v0) | ((u32)f2bf(v1)<<16);
        u32 pk1 = (u32)f2bf(v2) | ((u32)f2bf(v3)<<16);
        *(u64*)(rowp + tm*16 + q*4) = (u64)pk0 | ((u64)pk1<<32);
      }
    } else {
      #pragma unroll
      for (int tm=0;tm<8;tm++) {
        u32 pk0 = (u32)f2bf(acc[tm][0]+bias) | ((u32)f2bf(acc[tm][1]+bias)<<16);
        u32 pk1 = (u32)f2bf(acc[tm][2]+bias) | ((u32)f2bf(acc[tm][3]+bias)<<16);
        *(u64*)(rowp + tm*16 + q*4) = (u64)pk0 | ((u64)pk1<<32);
      }
    }
  }
}

// ---------------- K2: triangle einsum per h + gate multiply ----------------
// 512 threads / 8 waves, wave tile 64x32: acc[4][2]=32 VGPR (was acc[4][4]=64,
// est >128 total -> 2 waves/SIMD). Target VGPR<=128 -> 2x resident waves.
// XCD-chunked remap keeps each h-group's panels on one XCD's L2.
__global__ __launch_bounds__(512) void k_einsum(const u16* __restrict__ left_t, const u16* __restrict__ right_t,
    const u16* __restrict__ gate_t, u16* __restrict__ og_t) {
  __shared__ u16 smem[2*128*LDA];  // 36864 B
  u16* At = smem; u16* Bt = smem + 128*LDA;
  int bx = blockIdx.x;
  int wk = (bx & 7) * 144 + (bx >> 3);   // XCD-chunked bijection on 1152
  int h = wk / 9; int rem = wk % 9;
  int i0 = (rem/3)*128, j0 = (rem%3)*128;
  const u16* Ag = left_t + (size_t)h*M_;
  const u16* Bg = right_t + (size_t)h*M_;
  int t = threadIdx.x, w = t>>6, lane = t&63;
  int q = lane>>4, nl = lane&15;
  f32x4_t acc[4][2] = {};
  int m0 = (w&1)*64, nb0 = (w>>1)*32;
  for (int kb = 0; kb < N_; kb += 64) {
    { // stage A: left_t rows (i), k contiguous — direct vector copy (4 thr/row)
      int rr = t>>2, quarter = t&3;
      const u16* gp = Ag + (size_t)(i0+rr)*N_ + kb + quarter*16;
      u16* lp = At + rr*LDA + quarter*16;
      ((uint4*)lp)[0] = ((const uint4*)gp)[0];
      ((uint4*)lp)[1] = ((const uint4*)gp)[1];
    }
    { // stage B: register pair-transpose right_t[(kb+k)][j0+j] -> Bt[j][k] (swizzled)
      int kk2 = t>>4;          // 0..31 : k-pair
      int seg = t&15;          // j-chunk of 8
      const u16* g0 = Bg + (size_t)(kb + 2*kk2)*N_ + j0 + seg*8;
      const u16* g1 = g0 + N_;
      uint4 ra = ((const uint4*)g0)[0];
      uint4 rbv = ((const uint4*)g1)[0];
      u32 w0[4] = {ra.x,ra.y,ra.z,ra.w};
      u32 w1[4] = {rbv.x,rbv.y,rbv.z,rbv.w};
      u32 sw = (u32)(seg>>1) << 4;            // j>>4 constant over the 8-chunk
      char* bbytes = (char*)Bt;
      #pragma unroll
      for (int e=0;e<4;e++) {
        u32 lo = w0[e], hi = w1[e];
        u32 evenw = (lo & 0xffffu) | (hi << 16);
        u32 oddw  = (lo >> 16)     | (hi & 0xffff0000u);
        int je = seg*8 + 2*e;
        u32 byteE = ((u32)(je*LDA + 2*kk2) * 2u) ^ sw;
        u32 byteO = ((u32)((je+1)*LDA + 2*kk2) * 2u) ^ sw;
        *(u32*)(bbytes + byteE) = evenw;
        *(u32*)(bbytes + byteO) = oddw;
      }
    }
    __syncthreads();
    #pragma unroll
    for (int ks=0; ks<2; ks++) {
      int kel = ks*32 + q*8;
      bf16x8_t a[4], b[2];
      #pragma unroll
      for (int tm=0;tm<4;tm++) a[tm] = *(const bf16x8_t*)(At + (m0+tm*16+nl)*LDA + kel);
      #pragma unroll
      for (int tn=0;tn<2;tn++) {
        u32 swr = (u32)(((nb0>>4) + tn) & 7) << 4;
        b[tn] = *(const bf16x8_t*)((const char*)Bt + ((u32)(((nb0+tn*16+nl)*LDA + kel)*2) ^ swr));
      }
      #pragma unroll
      for (int tm=0;tm<4;tm++)
        #pragma unroll
        for (int tn=0;tn<2;tn++)
          acc[tm][tn] = __builtin_amdgcn_mfma_f32_16x16x32_bf16(a[tm], b[tn], acc[tm][tn], 0,0,0);
    }
    __syncthreads();
  }
  // epilogue: acc -> LDS bf16 [m][n], then gate-multiplied coalesced store (og_t[h][r])
  u16* Ot = smem;  // 128*LDT u16 = 34816 B <= 36864
  #pragma unroll
  for (int tm=0;tm<4;tm++)
    #pragma unroll
    for (int tn=0;tn<2;tn++)
      #pragma unroll
      for (int p=0;p<4;p++) {
        int m = m0 + tm*16 + q*4 + p;
        int n = nb0 + tn*16 + nl;
        Ot[m*LDT + n] = f2bf(acc[tm][tn][p]);
      }
  __syncthreads();
  {
    int m = t>>2, hq = t&3;
    size_t rbase = (size_t)h*M_ + (size_t)(i0+m)*N_ + j0 + hq*32;
    const uint4* gg = (const uint4*)(gate_t + rbase);
    const uint4* lo = (const uint4*)(Ot + m*LDT + hq*32);
    uint4* od = (uint4*)(og_t + rbase);
    #pragma unroll
    for (int i=0;i<4;i++) {
      uint4 gv = gg[i]; uint4 ov = lo[i];
      u32 ga[4] = {gv.x,gv.y,gv.z,gv.w};
      u32 oa[4] = {ov.x,ov.y,ov.z,ov.w};
      u32 ra2[4];
      #pragma unroll
      for (int e=0;e<4;e++) {
        float g0 = bf2f((u16)(ga[e]&0xffffu)), g1 = bf2f((u16)(ga[e]>>16));
        float o0 = bf2f((u16)(oa[e]&0xffffu)), o1 = bf2f((u16)(oa[e]>>16));
        ra2[e] = (u32)f2bf(o0*g0) | ((u32)f2bf(o1*g1)<<16);
      }
      od[i] = make_uint4(ra2[0],ra2[1],ra2[2],ra2[3]);
    }
  }
}

// ---------------- K3: og @ Wo + bo + pair, rowwise LN, fp32 out ----------------
// 512 threads / 8 waves, wave = 16 m-rows x 128 n: acc[8]=32 VGPR (was acc[2][8]=64,
// est >128 total). Target VGPR<=128 -> 2x resident waves.
__global__ __launch_bounds__(512) void k_final(const u16* __restrict__ og_t, const u16* __restrict__ wot,
    const float* __restrict__ pair, const float* __restrict__ bo,
    const float* __restrict__ ng, const float* __restrict__ nb_,
    float* __restrict__ out) {
  __shared__ u16 smem[2*128*LDW];  // 36864 B
  u16* At = smem; u16* Wt = smem + 128*LDW;
  int bx = blockIdx.x;
  int r0 = bx * 128;
  int t = threadIdx.x, w = t>>6, lane = t&63;
  int q = lane>>4, nl = lane&15;
  f32x4_t acc[8] = {};
  int m0 = w*16;
  for (int c0 = 0; c0 < 128; c0 += 64) {
    { // stage A with transpose: og_t[(c0+hh)*M + r0+r] -> At[r][hh]  (8 thr/row)
      int hh = t>>3, seg = t&7;
      const u16* gp = og_t + (size_t)(c0+hh)*M_ + r0 + seg*16;
      uint4 b0 = ((const uint4*)gp)[0];
      uint4 b1 = ((const uint4*)gp)[1];
      u32 xs[8] = {b0.x,b0.y,b0.z,b0.w,b1.x,b1.y,b1.z,b1.w};
      #pragma unroll
      for (int e=0;e<8;e++) {
        int rb = seg*16 + 2*e;
        At[(rb+0)*LDW+hh] = (u16)(xs[e]&0xffffu);
        At[(rb+1)*LDW+hh] = (u16)(xs[e]>>16);
      }
    }
    { // stage Wo chunk: Wt[c][h']  (4 thr/row)
      int c = t>>2, q4 = t&3;
      const u16* gp = wot + (size_t)c*128 + c0 + q4*16;
      u16* lp = Wt + c*LDW + q4*16;
      ((uint4*)lp)[0] = ((const uint4*)gp)[0];
      ((uint4*)lp)[1] = ((const uint4*)gp)[1];
    }
    __syncthreads();
    #pragma unroll
    for (int ks=0; ks<2; ks++) {
      int kel = ks*32 + q*8;
      bf16x8_t a = *(const bf16x8_t*)(At + (m0+nl)*LDW + kel);
      bf16x8_t b[8];
      #pragma unroll
      for (int tn=0;tn<8;tn++) b[tn] = *(const bf16x8_t*)(Wt + (tn*16+nl)*LDW + kel);
      #pragma unroll
      for (int tn=0;tn<8;tn++)
        acc[tn] = __builtin_amdgcn_mfma_f32_16x16x32_bf16(a, b[tn], acc[tn], 0,0,0);
    }
    __syncthreads();
  }
  // epilogue: residual + bias, transpose-free rowwise LN via 16-lane shfl reduction
  float rsum[4], rsq[4];
  #pragma unroll
  for (int p=0;p<4;p++) { rsum[p]=0.f; rsq[p]=0.f; }
  #pragma unroll
  for (int tn=0;tn<8;tn++) {
    int n = tn*16 + nl;
    float bb = bo[n];
    #pragma unroll
    for (int p=0;p<4;p++) {
      int m = m0 + q*4 + p;
      float v = acc[tn][p] + bb + pair[(size_t)(r0+m)*128 + n];
      acc[tn][p] = v;
      rsum[p] += v;
      rsq[p]  += v*v;
    }
  }
  #pragma unroll
  for (int msk=1; msk<16; msk<<=1) {
    #pragma unroll
    for (int p=0;p<4;p++) {
      rsum[p] += __shfl_xor(rsum[p], msk, 64);
      rsq[p]  += __shfl_xor(rsq[p],  msk, 64);
    }
  }
  #pragma unroll
  for (int p=0;p<4;p++) {
    float mu = rsum[p] * (1.f/128.f);
    float var = rsq[p]*(1.f/128.f) - mu*mu;
    rsum[p] = mu;
    rsq[p] = rsqrtf(var + 1e-5f);
  }
  #pragma unroll
  for (int tn=0;tn<8;tn++) {
    int n = tn*16 + nl;
    float g = ng[n], b2 = nb_[n];
    #pragma unroll
    for (int p=0;p<4;p++) {
      int m = m0 + q*4 + p;
      out[(size_t)(r0+m)*128 + n] = (acc[tn][p] - rsum[p]) * rsq[p] * g + b2;
    }
  }
}

extern "C" void kernel_launch(void* const* d_in, const int* in_sizes, int n_in,
                              void* d_out, int out_size, void* d_ws, size_t ws_size,
                              hipStream_t stream) {
  (void)in_sizes; (void)n_in; (void)out_size; (void)ws_size;
  const float* pair   = (const float*)d_in[0];
  const float* ln_l_g = (const float*)d_in[1];
  const float* ln_l_b = (const float*)d_in[2];
  const float* ln_r_g = (const float*)d_in[3];
  const float* ln_r_b = (const float*)d_in[4];
  const float* Wl = (const float*)d_in[5];
  const float* bl = (const float*)d_in[6];
  const float* Wr = (const float*)d_in[7];
  const float* br = (const float*)d_in[8];
  const float* Wg = (const float*)d_in[9];
  const float* bg = (const float*)d_in[10];
  const float* Wo = (const float*)d_in[11];
  const float* bo = (const float*)d_in[12];
  const float* n_g = (const float*)d_in[13];
  const float* n_b = (const float*)d_in[14];

  char* ws = (char*)d_ws;
  const size_t SZ = (size_t)M_*128*sizeof(u16);         // 37,748,736 B
  u16*  og_t    = (u16*)(ws);                           // written by k_einsum
  u16*  gate_t  = (u16*)(ws + SZ);
  u16*  wcat    = (u16*)(ws + 2*SZ);
  float* bcat   = (float*)(ws + 2*SZ + 98304);
  float* sgp    = (float*)(ws + 2*SZ + 98304 + 1536);
  u16*  wot     = (u16*)(ws + 2*SZ + 98304 + 1536 + 512);

  // left_t / right_t live in d_out until k_final overwrites it with the result
  u16* left_t   = (u16*)d_out;
  u16* right_t  = (u16*)d_out + (size_t)M_*128;

  k_prep<<<258, 256, 0, stream>>>(ln_l_g, ln_r_g, Wl, Wr, Wg, Wo,
                                  ln_l_b, ln_r_b, bl, br, bg, wcat, wot, bcat, sgp);
  k_projln<<<1152, 512, 0, stream>>>(pair, wcat, bcat, sgp, left_t, right_t, gate_t);
  k_einsum<<<1152, 512, 0, stream>>>(left_t, right_t, gate_t, og_t);
  k_final<<<1152, 512, 0, stream>>>(og_t, wot, pair, bo, n_g, n_b, (float*)d_out);
}

// Round 6
// 268.856 us; speedup vs baseline: 1.5827x; 1.0094x over previous
//
#include <hip/hip_runtime.h>
#include <hip/hip_bf16.h>

#define N_ 384
#define C_ 128
#define M_ (N_*N_)   // 147456 rows (i*384+j)

typedef __attribute__((ext_vector_type(8))) short bf16x8_t;
typedef __attribute__((ext_vector_type(4))) float f32x4_t;
typedef unsigned int u32;
typedef unsigned short u16;
typedef unsigned long long u64;

__device__ __forceinline__ u16 f2bf(float f) {
  u32 u = __builtin_bit_cast(u32, f);
  u32 r = (u + 0x7FFFu + ((u >> 16) & 1u)) >> 16;
  return (u16)r;
}
__device__ __forceinline__ float bf2f(u16 h) {
  u32 u = ((u32)h) << 16;
  return __builtin_bit_cast(float, u);
}

// ---------------- fused prep kernel ----------------
__global__ __launch_bounds__(256) void k_prep(const float* __restrict__ lg, const float* __restrict__ rg,
    const float* __restrict__ Wl, const float* __restrict__ Wr, const float* __restrict__ Wg,
    const float* __restrict__ Wo,
    const float* __restrict__ lb, const float* __restrict__ rb,
    const float* __restrict__ bl, const float* __restrict__ br, const float* __restrict__ bg,
    u16* __restrict__ wcat, u16* __restrict__ wot,
    float* __restrict__ bcat, float* __restrict__ sg) {
  int bx = blockIdx.x, t = threadIdx.x;
  if (bx < 256) {
    int idx = bx*256 + t;
    if (idx < 49152) {
      int n = idx >> 7, k = idx & 127;
      float v;
      if (n < 128)      v = lg[k] * Wl[k*128 + n];
      else if (n < 256) v = rg[k] * Wr[k*128 + (n-128)];
      else              v = Wg[k*128 + (n-256)];
      wcat[idx] = f2bf(v);
    } else {
      int i2 = idx - 49152;           // < 16384
      int c = i2 >> 7, h = i2 & 127;
      wot[i2] = f2bf(Wo[h*128 + c]);
    }
  } else if (bx == 256) {
    float s = 0.f;
    if (t < 128)      { for (int k=0;k<128;k++) s += lb[k]*Wl[k*128+t];       s += bl[t];     bcat[t] = s; }
    else              { int hh=t-128; for (int k=0;k<128;k++) s += rb[k]*Wr[k*128+hh]; s += br[hh]; bcat[t] = s; }
  } else {
    if (t < 128)      { bcat[256+t] = bg[t]; }
    else              { int hh = t-128; float s=0.f; for (int k=0;k<128;k++) s += Wg[k*128+hh]; sg[hh] = s; }
  }
}

#define LDK 136  // u16 stride of staged 128-k rows
#define LDA 72
#define LDW 72
#define LDT 136

// ---------------- K1: fused LN + three projections ----------------
// NEW tile-major layout: lr[rb][256][128] (n=h left, 128+h right), gate[rb][128][128].
// Each block writes ONE contiguous 64KB region + one 32KB region (was 384 scattered
// 256B islands at 294KB stride -> DRAM page thrash, 1.9 TB/s cap).
__global__ __launch_bounds__(512) void k_projln(const float* __restrict__ pair,
    const u16* __restrict__ wcat, const float* __restrict__ bcat, const float* __restrict__ sg,
    u16* __restrict__ lr_, u16* __restrict__ gate_) {
  __shared__ u16 At[128*LDK];   // 34816 B
  __shared__ float mu_s[128];
  __shared__ float irs_s[128];
  int bx = blockIdx.x;
  int r0 = bx * 128;
  int t = threadIdx.x, w = t>>6, lane = t&63;
  int q = lane>>4, nl = lane&15;

  // ---- LN phase: 4 threads per row (executed ONCE) ----
  {
    int rr = t >> 2, quarter = t & 3;
    const float4* gp = (const float4*)(pair + (size_t)(r0+rr)*128 + quarter*32);
    float4 v[8];
    #pragma unroll
    for (int i=0;i<8;i++) v[i] = gp[i];
    float s=0.f, qq=0.f;
    #pragma unroll
    for (int i=0;i<8;i++) {
      s  += v[i].x + v[i].y + v[i].z + v[i].w;
      qq += v[i].x*v[i].x + v[i].y*v[i].y + v[i].z*v[i].z + v[i].w*v[i].w;
    }
    s  += __shfl_xor(s, 1, 64);
    s  += __shfl_xor(s, 2, 64);
    qq += __shfl_xor(qq, 1, 64);
    qq += __shfl_xor(qq, 2, 64);
    float mu = s * (1.f/128.f);
    float var = qq*(1.f/128.f) - mu*mu;
    float rstd = rsqrtf(var + 1e-5f);
    if (quarter == 0) { mu_s[rr] = mu; irs_s[rr] = 1.0f/rstd; }
    u32* lp = (u32*)(At + rr*LDK + quarter*32);
    #pragma unroll
    for (int i=0;i<4;i++) {
      u32 p0 = (u32)f2bf((v[2*i].x-mu)*rstd)   | ((u32)f2bf((v[2*i].y-mu)*rstd)<<16);
      u32 p1 = (u32)f2bf((v[2*i].z-mu)*rstd)   | ((u32)f2bf((v[2*i].w-mu)*rstd)<<16);
      u32 p2 = (u32)f2bf((v[2*i+1].x-mu)*rstd) | ((u32)f2bf((v[2*i+1].y-mu)*rstd)<<16);
      u32 p3 = (u32)f2bf((v[2*i+1].z-mu)*rstd) | ((u32)f2bf((v[2*i+1].w-mu)*rstd)<<16);
      ((uint4*)lp)[i] = make_uint4(p0,p1,p2,p3);
    }
  }
  __syncthreads();

  #pragma unroll 1
  for (int nb = 0; nb < 3; ++nb) {
    const u16* bbase = wcat + (size_t)(nb*128)*128;
    f32x4_t acc[8] = {};   // [tm] ; m = tm*16+q*4+p, n = w*16+nl
    #pragma unroll
    for (int ks=0; ks<4; ks++) {
      int kel = ks*32 + q*8;
      bf16x8_t b = *(const bf16x8_t*)(bbase + (size_t)(w*16 + nl)*128 + kel);
      #pragma unroll
      for (int tm=0;tm<8;tm++) {
        bf16x8_t a = *(const bf16x8_t*)(At + (tm*16+nl)*LDK + kel);
        acc[tm] = __builtin_amdgcn_mfma_f32_16x16x32_bf16(a, b, acc[tm], 0,0,0);
      }
    }
    int n = w*16 + nl;
    float bias = bcat[nb*128 + n];
    u16* rowp;
    if (nb == 0)      rowp = lr_   + ((size_t)bx*256 + n)*128;
    else if (nb == 1) rowp = lr_   + ((size_t)bx*256 + 128 + n)*128;
    else              rowp = gate_ + ((size_t)bx*128 + n)*128;
    if (nb == 2) {
      float sgn = sg[n];
      #pragma unroll
      for (int tm=0;tm<8;tm++) {
        f32x4_t mu4 = *(const f32x4_t*)(mu_s  + tm*16 + q*4);
        f32x4_t ir4 = *(const f32x4_t*)(irs_s + tm*16 + q*4);
        float v0 = acc[tm][0]*ir4[0] + mu4[0]*sgn + bias;
        float v1 = acc[tm][1]*ir4[1] + mu4[1]*sgn + bias;
        float v2 = acc[tm][2]*ir4[2] + mu4[2]*sgn + bias;
        float v3 = acc[tm][3]*ir4[3] + mu4[3]*sgn + bias;
        v0 = 1.0f/(1.0f+__expf(-v0));
        v1 = 1.0f/(1.0f+__expf(-v1));
        v2 = 1.0f/(1.0f+__expf(-v2));
        v3 = 1.0f/(1.0f+__expf(-v3));
        u32 pk0 = (u32)f2bf(v0) | ((u32)f2bf(v1)<<16);
        u32 pk1 = (u32)f2bf(v2) | ((u32)f2bf(v3)<<16);
        *(u64*)(rowp + tm*16 + q*4) = (u64)pk0 | ((u64)pk1<<32);
      }
    } else {
      #pragma unroll
      for (int tm=0;tm<8;tm++) {
        u32 pk0 = (u32)f2bf(acc[tm][0]+bias) | ((u32)f2bf(acc[tm][1]+bias)<<16);
        u32 pk1 = (u32)f2bf(acc[tm][2]+bias) | ((u32)f2bf(acc[tm][3]+bias)<<16);
        *(u64*)(rowp + tm*16 + q*4) = (u64)pk0 | ((u64)pk1<<32);
      }
    }
  }
}

// ---------------- K2: triangle einsum per h + gate multiply ----------------
// Reads from tile-major lr[rb][256][128] / gate[rb][128][128]; writes og[rb][128][128].
// XCD remap co-schedules the 16 consecutive-h blocks per XCD: their reads/writes at
// adjacent middle-index h aggregate into 4KB-dense DRAM regions; L2 absorbs 3x j-reuse.
__global__ __launch_bounds__(512) void k_einsum(const u16* __restrict__ lr_,
    const u16* __restrict__ gate_, u16* __restrict__ og_) {
  __shared__ u16 smem[2*128*LDA];  // 36864 B
  u16* At = smem; u16* Bt = smem + 128*LDA;
  int bx = blockIdx.x;
  int wk = (bx & 7) * 144 + (bx >> 3);   // XCD-chunked bijection on 1152
  int h = wk / 9; int rem = wk % 9;
  int i0 = (rem/3)*128, j0c = rem%3;     // j0 = j0c*128
  int t = threadIdx.x, w = t>>6, lane = t&63;
  int q = lane>>4, nl = lane&15;
  f32x4_t acc[4][2] = {};
  int m0 = (w&1)*64, nb0 = (w>>1)*32;
  for (int kb = 0; kb < N_; kb += 64) {
    int c = kb >> 7, off = kb & 127;
    { // stage A: left rows (i): lr[(i*3+c)][h][off..off+64] — 128B pieces (4 thr/row)
      int rr = t>>2, quarter = t&3;
      const u16* gp = lr_ + (((size_t)(i0+rr)*3 + c)*256 + h)*128 + off + quarter*16;
      u16* lp = At + rr*LDA + quarter*16;
      ((uint4*)lp)[0] = ((const uint4*)gp)[0];
      ((uint4*)lp)[1] = ((const uint4*)gp)[1];
    }
    { // stage B with transpose: right row k: lr[(k*3+j0c)][128+h][j] -> Bt[j][k] (swizzled)
      int kk2 = t>>4;          // 0..31 : k-pair
      int seg = t&15;          // j-chunk of 8
      const u16* g0 = lr_ + (((size_t)(kb + 2*kk2)*3 + j0c)*256 + 128 + h)*128 + seg*8;
      const u16* g1 = g0 + 3*256*128;   // next k row
      uint4 ra = ((const uint4*)g0)[0];
      uint4 rbv = ((const uint4*)g1)[0];
      u32 w0[4] = {ra.x,ra.y,ra.z,ra.w};
      u32 w1[4] = {rbv.x,rbv.y,rbv.z,rbv.w};
      u32 sw = (u32)(seg>>1) << 4;            // j>>4 constant over the 8-chunk
      char* bbytes = (char*)Bt;
      #pragma unroll
      for (int e=0;e<4;e++) {
        u32 lo = w0[e], hi = w1[e];
        u32 evenw = (lo & 0xffffu) | (hi << 16);
        u32 oddw  = (lo >> 16)     | (hi & 0xffff0000u);
        int je = seg*8 + 2*e;
        u32 byteE = ((u32)(je*LDA + 2*kk2) * 2u) ^ sw;
        u32 byteO = ((u32)((je+1)*LDA + 2*kk2) * 2u) ^ sw;
        *(u32*)(bbytes + byteE) = evenw;
        *(u32*)(bbytes + byteO) = oddw;
      }
    }
    __syncthreads();
    #pragma unroll
    for (int ks=0; ks<2; ks++) {
      int kel = ks*32 + q*8;
      bf16x8_t a[4], b[2];
      #pragma unroll
      for (int tm=0;tm<4;tm++) a[tm] = *(const bf16x8_t*)(At + (m0+tm*16+nl)*LDA + kel);
      #pragma unroll
      for (int tn=0;tn<2;tn++) {
        u32 swr = (u32)(((nb0>>4) + tn) & 7) << 4;
        b[tn] = *(const bf16x8_t*)((const char*)Bt + ((u32)(((nb0+tn*16+nl)*LDA + kel)*2) ^ swr));
      }
      #pragma unroll
      for (int tm=0;tm<4;tm++)
        #pragma unroll
        for (int tn=0;tn<2;tn++)
          acc[tm][tn] = __builtin_amdgcn_mfma_f32_16x16x32_bf16(a[tm], b[tn], acc[tm][tn], 0,0,0);
    }
    __syncthreads();
  }
  // epilogue: acc -> LDS bf16 [m][n], then gate-multiplied coalesced store (og[rb][h][j])
  u16* Ot = smem;  // 128*LDT u16 = 34816 B <= 36864
  #pragma unroll
  for (int tm=0;tm<4;tm++)
    #pragma unroll
    for (int tn=0;tn<2;tn++)
      #pragma unroll
      for (int p=0;p<4;p++) {
        int m = m0 + tm*16 + q*4 + p;
        int n = nb0 + tn*16 + nl;
        Ot[m*LDT + n] = f2bf(acc[tm][tn][p]);
      }
  __syncthreads();
  {
    int m = t>>2, hq = t&3;
    size_t gbase = (((size_t)(i0+m)*3 + j0c)*128 + h)*128 + hq*32;
    const uint4* gg = (const uint4*)(gate_ + gbase);
    const uint4* lo = (const uint4*)(Ot + m*LDT + hq*32);
    uint4* od = (uint4*)(og_ + gbase);
    #pragma unroll
    for (int i=0;i<4;i++) {
      uint4 gv = gg[i]; uint4 ov = lo[i];
      u32 ga[4] = {gv.x,gv.y,gv.z,gv.w};
      u32 oa[4] = {ov.x,ov.y,ov.z,ov.w};
      u32 ra2[4];
      #pragma unroll
      for (int e=0;e<4;e++) {
        float g0 = bf2f((u16)(ga[e]&0xffffu)), g1 = bf2f((u16)(ga[e]>>16));
        float o0 = bf2f((u16)(oa[e]&0xffffu)), o1 = bf2f((u16)(oa[e]>>16));
        ra2[e] = (u32)f2bf(o0*g0) | ((u32)f2bf(o1*g1)<<16);
      }
      od[i] = make_uint4(ra2[0],ra2[1],ra2[2],ra2[3]);
    }
  }
}

// ---------------- K3: og @ Wo + bo + pair, rowwise LN, fp32 out ----------------
// og read is now ONE contiguous 32KB region per block: og[bx][hh][ri].
__global__ __launch_bounds__(512) void k_final(const u16* __restrict__ og_, const u16* __restrict__ wot,
    const float* __restrict__ pair, const float* __restrict__ bo,
    const float* __restrict__ ng, const float* __restrict__ nb_,
    float* __restrict__ out) {
  __shared__ u16 smem[2*128*LDW];  // 36864 B
  u16* At = smem; u16* Wt = smem + 128*LDW;
  int bx = blockIdx.x;
  int r0 = bx * 128;
  int t = threadIdx.x, w = t>>6, lane = t&63;
  int q = lane>>4, nl = lane&15;
  f32x4_t acc[8] = {};
  int m0 = w*16;
  for (int c0 = 0; c0 < 128; c0 += 64) {
    { // stage A with transpose: og[bx][c0+hh][r] -> At[r][hh]  (8 thr/row)
      int hh = t>>3, seg = t&7;
      const u16* gp = og_ + ((size_t)bx*128 + (c0+hh))*128 + seg*16;
      uint4 b0 = ((const uint4*)gp)[0];
      uint4 b1 = ((const uint4*)gp)[1];
      u32 xs[8] = {b0.x,b0.y,b0.z,b0.w,b1.x,b1.y,b1.z,b1.w};
      #pragma unroll
      for (int e=0;e<8;e++) {
        int rb = seg*16 + 2*e;
        At[(rb+0)*LDW+hh] = (u16)(xs[e]&0xffffu);
        At[(rb+1)*LDW+hh] = (u16)(xs[e]>>16);
      }
    }
    { // stage Wo chunk: Wt[c][h']  (4 thr/row)
      int c = t>>2, q4 = t&3;
      const u16* gp = wot + (size_t)c*128 + c0 + q4*16;
      u16* lp = Wt + c*LDW + q4*16;
      ((uint4*)lp)[0] = ((const uint4*)gp)[0];
      ((uint4*)lp)[1] = ((const uint4*)gp)[1];
    }
    __syncthreads();
    #pragma unroll
    for (int ks=0; ks<2; ks++) {
      int kel = ks*32 + q*8;
      bf16x8_t a = *(const bf16x8_t*)(At + (m0+nl)*LDW + kel);
      bf16x8_t b[8];
      #pragma unroll
      for (int tn=0;tn<8;tn++) b[tn] = *(const bf16x8_t*)(Wt + (tn*16+nl)*LDW + kel);
      #pragma unroll
      for (int tn=0;tn<8;tn++)
        acc[tn] = __builtin_amdgcn_mfma_f32_16x16x32_bf16(a, b[tn], acc[tn], 0,0,0);
    }
    __syncthreads();
  }
  // epilogue: residual + bias, transpose-free rowwise LN via 16-lane shfl reduction
  float rsum[4], rsq[4];
  #pragma unroll
  for (int p=0;p<4;p++) { rsum[p]=0.f; rsq[p]=0.f; }
  #pragma unroll
  for (int tn=0;tn<8;tn++) {
    int n = tn*16 + nl;
    float bb = bo[n];
    #pragma unroll
    for (int p=0;p<4;p++) {
      int m = m0 + q*4 + p;
      float v = acc[tn][p] + bb + pair[(size_t)(r0+m)*128 + n];
      acc[tn][p] = v;
      rsum[p] += v;
      rsq[p]  += v*v;
    }
  }
  #pragma unroll
  for (int msk=1; msk<16; msk<<=1) {
    #pragma unroll
    for (int p=0;p<4;p++) {
      rsum[p] += __shfl_xor(rsum[p], msk, 64);
      rsq[p]  += __shfl_xor(rsq[p],  msk, 64);
    }
  }
  #pragma unroll
  for (int p=0;p<4;p++) {
    float mu = rsum[p] * (1.f/128.f);
    float var = rsq[p]*(1.f/128.f) - mu*mu;
    rsum[p] = mu;
    rsq[p] = rsqrtf(var + 1e-5f);
  }
  #pragma unroll
  for (int tn=0;tn<8;tn++) {
    int n = tn*16 + nl;
    float g = ng[n], b2 = nb_[n];
    #pragma unroll
    for (int p=0;p<4;p++) {
      int m = m0 + q*4 + p;
      out[(size_t)(r0+m)*128 + n] = (acc[tn][p] - rsum[p]) * rsq[p] * g + b2;
    }
  }
}

extern "C" void kernel_launch(void* const* d_in, const int* in_sizes, int n_in,
                              void* d_out, int out_size, void* d_ws, size_t ws_size,
                              hipStream_t stream) {
  (void)in_sizes; (void)n_in; (void)out_size; (void)ws_size;
  const float* pair   = (const float*)d_in[0];
  const float* ln_l_g = (const float*)d_in[1];
  const float* ln_l_b = (const float*)d_in[2];
  const float* ln_r_g = (const float*)d_in[3];
  const float* ln_r_b = (const float*)d_in[4];
  const float* Wl = (const float*)d_in[5];
  const float* bl = (const float*)d_in[6];
  const float* Wr = (const float*)d_in[7];
  const float* br = (const float*)d_in[8];
  const float* Wg = (const float*)d_in[9];
  const float* bg = (const float*)d_in[10];
  const float* Wo = (const float*)d_in[11];
  const float* bo = (const float*)d_in[12];
  const float* n_g = (const float*)d_in[13];
  const float* n_b = (const float*)d_in[14];

  char* ws = (char*)d_ws;
  const size_t SZ = (size_t)M_*128*sizeof(u16);         // 37,748,736 B
  u16*  og    = (u16*)(ws);                             // [1152][128][128]
  u16*  gate  = (u16*)(ws + SZ);                        // [1152][128][128]
  u16*  wcat  = (u16*)(ws + 2*SZ);
  float* bcat = (float*)(ws + 2*SZ + 98304);
  float* sgp  = (float*)(ws + 2*SZ + 98304 + 1536);
  u16*  wot   = (u16*)(ws + 2*SZ + 98304 + 1536 + 512);

  // lr[1152][256][128] (left|right cat) lives in d_out (exactly M_*128*4 B),
  // consumed by k_einsum before k_final overwrites d_out with the fp32 result.
  u16* lr = (u16*)d_out;

  k_prep<<<258, 256, 0, stream>>>(ln_l_g, ln_r_g, Wl, Wr, Wg, Wo,
                                  ln_l_b, ln_r_b, bl, br, bg, wcat, wot, bcat, sgp);
  k_projln<<<1152, 512, 0, stream>>>(pair, wcat, bcat, sgp, lr, gate);
  k_einsum<<<1152, 512, 0, stream>>>(lr, gate, og);
  k_final<<<1152, 512, 0, stream>>>(og, wot, pair, bo, n_g, n_b, (float*)d_out);
}

// Round 7
// 263.421 us; speedup vs baseline: 1.6154x; 1.0206x over previous
//
#include <hip/hip_runtime.h>
#include <hip/hip_bf16.h>

#define N_ 384
#define C_ 128
#define M_ (N_*N_)   // 147456 rows (i*384+j)

typedef __attribute__((ext_vector_type(8))) short bf16x8_t;
typedef __attribute__((ext_vector_type(4))) float f32x4_t;
typedef unsigned int u32;
typedef unsigned short u16;
typedef unsigned long long u64;

__device__ __forceinline__ u16 f2bf(float f) {
  u32 u = __builtin_bit_cast(u32, f);
  u32 r = (u + 0x7FFFu + ((u >> 16) & 1u)) >> 16;
  return (u16)r;
}
__device__ __forceinline__ float bf2f(u16 h) {
  u32 u = ((u32)h) << 16;
  return __builtin_bit_cast(float, u);
}

// ---------------- fused prep kernel ----------------
__global__ __launch_bounds__(256) void k_prep(const float* __restrict__ lg, const float* __restrict__ rg,
    const float* __restrict__ Wl, const float* __restrict__ Wr, const float* __restrict__ Wg,
    const float* __restrict__ Wo,
    const float* __restrict__ lb, const float* __restrict__ rb,
    const float* __restrict__ bl, const float* __restrict__ br, const float* __restrict__ bg,
    u16* __restrict__ wcat, u16* __restrict__ wot,
    float* __restrict__ bcat, float* __restrict__ sg) {
  int bx = blockIdx.x, t = threadIdx.x;
  if (bx < 256) {
    int idx = bx*256 + t;
    if (idx < 49152) {
      int n = idx >> 7, k = idx & 127;
      float v;
      if (n < 128)      v = lg[k] * Wl[k*128 + n];
      else if (n < 256) v = rg[k] * Wr[k*128 + (n-128)];
      else              v = Wg[k*128 + (n-256)];
      wcat[idx] = f2bf(v);
    } else {
      int i2 = idx - 49152;           // < 16384
      int c = i2 >> 7, h = i2 & 127;
      wot[i2] = f2bf(Wo[h*128 + c]);
    }
  } else if (bx == 256) {
    float s = 0.f;
    if (t < 128)      { for (int k=0;k<128;k++) s += lb[k]*Wl[k*128+t];       s += bl[t];     bcat[t] = s; }
    else              { int hh=t-128; for (int k=0;k<128;k++) s += rb[k]*Wr[k*128+hh]; s += br[hh]; bcat[t] = s; }
  } else {
    if (t < 128)      { bcat[256+t] = bg[t]; }
    else              { int hh = t-128; float s=0.f; for (int k=0;k<128;k++) s += Wg[k*128+hh]; sg[hh] = s; }
  }
}

#define LDK 136  // u16 stride of staged 128-k rows
#define LDA 72
#define LDW 72
#define LDW2 136
#define LDT 136

// ---------------- K1: fused LN + three projections (unchanged control, 79us) ----------------
__global__ __launch_bounds__(512) void k_projln(const float* __restrict__ pair,
    const u16* __restrict__ wcat, const float* __restrict__ bcat, const float* __restrict__ sg,
    u16* __restrict__ lr_, u16* __restrict__ gate_) {
  __shared__ u16 At[128*LDK];   // 34816 B
  __shared__ float mu_s[128];
  __shared__ float irs_s[128];
  int bx = blockIdx.x;
  int r0 = bx * 128;
  int t = threadIdx.x, w = t>>6, lane = t&63;
  int q = lane>>4, nl = lane&15;

  // ---- LN phase: 4 threads per row (executed ONCE) ----
  {
    int rr = t >> 2, quarter = t & 3;
    const float4* gp = (const float4*)(pair + (size_t)(r0+rr)*128 + quarter*32);
    float4 v[8];
    #pragma unroll
    for (int i=0;i<8;i++) v[i] = gp[i];
    float s=0.f, qq=0.f;
    #pragma unroll
    for (int i=0;i<8;i++) {
      s  += v[i].x + v[i].y + v[i].z + v[i].w;
      qq += v[i].x*v[i].x + v[i].y*v[i].y + v[i].z*v[i].z + v[i].w*v[i].w;
    }
    s  += __shfl_xor(s, 1, 64);
    s  += __shfl_xor(s, 2, 64);
    qq += __shfl_xor(qq, 1, 64);
    qq += __shfl_xor(qq, 2, 64);
    float mu = s * (1.f/128.f);
    float var = qq*(1.f/128.f) - mu*mu;
    float rstd = rsqrtf(var + 1e-5f);
    if (quarter == 0) { mu_s[rr] = mu; irs_s[rr] = 1.0f/rstd; }
    u32* lp = (u32*)(At + rr*LDK + quarter*32);
    #pragma unroll
    for (int i=0;i<4;i++) {
      u32 p0 = (u32)f2bf((v[2*i].x-mu)*rstd)   | ((u32)f2bf((v[2*i].y-mu)*rstd)<<16);
      u32 p1 = (u32)f2bf((v[2*i].z-mu)*rstd)   | ((u32)f2bf((v[2*i].w-mu)*rstd)<<16);
      u32 p2 = (u32)f2bf((v[2*i+1].x-mu)*rstd) | ((u32)f2bf((v[2*i+1].y-mu)*rstd)<<16);
      u32 p3 = (u32)f2bf((v[2*i+1].z-mu)*rstd) | ((u32)f2bf((v[2*i+1].w-mu)*rstd)<<16);
      ((uint4*)lp)[i] = make_uint4(p0,p1,p2,p3);
    }
  }
  __syncthreads();

  #pragma unroll 1
  for (int nb = 0; nb < 3; ++nb) {
    const u16* bbase = wcat + (size_t)(nb*128)*128;
    f32x4_t acc[8] = {};   // [tm] ; m = tm*16+q*4+p, n = w*16+nl
    #pragma unroll
    for (int ks=0; ks<4; ks++) {
      int kel = ks*32 + q*8;
      bf16x8_t b = *(const bf16x8_t*)(bbase + (size_t)(w*16 + nl)*128 + kel);
      #pragma unroll
      for (int tm=0;tm<8;tm++) {
        bf16x8_t a = *(const bf16x8_t*)(At + (tm*16+nl)*LDK + kel);
        acc[tm] = __builtin_amdgcn_mfma_f32_16x16x32_bf16(a, b, acc[tm], 0,0,0);
      }
    }
    int n = w*16 + nl;
    float bias = bcat[nb*128 + n];
    u16* rowp;
    if (nb == 0)      rowp = lr_   + ((size_t)bx*256 + n)*128;
    else if (nb == 1) rowp = lr_   + ((size_t)bx*256 + 128 + n)*128;
    else              rowp = gate_ + ((size_t)bx*128 + n)*128;
    if (nb == 2) {
      float sgn = sg[n];
      #pragma unroll
      for (int tm=0;tm<8;tm++) {
        f32x4_t mu4 = *(const f32x4_t*)(mu_s  + tm*16 + q*4);
        f32x4_t ir4 = *(const f32x4_t*)(irs_s + tm*16 + q*4);
        float v0 = acc[tm][0]*ir4[0] + mu4[0]*sgn + bias;
        float v1 = acc[tm][1]*ir4[1] + mu4[1]*sgn + bias;
        float v2 = acc[tm][2]*ir4[2] + mu4[2]*sgn + bias;
        float v3 = acc[tm][3]*ir4[3] + mu4[3]*sgn + bias;
        v0 = 1.0f/(1.0f+__expf(-v0));
        v1 = 1.0f/(1.0f+__expf(-v1));
        v2 = 1.0f/(1.0f+__expf(-v2));
        v3 = 1.0f/(1.0f+__expf(-v3));
        u32 pk0 = (u32)f2bf(v0) | ((u32)f2bf(v1)<<16);
        u32 pk1 = (u32)f2bf(v2) | ((u32)f2bf(v3)<<16);
        *(u64*)(rowp + tm*16 + q*4) = (u64)pk0 | ((u64)pk1<<32);
      }
    } else {
      #pragma unroll
      for (int tm=0;tm<8;tm++) {
        u32 pk0 = (u32)f2bf(acc[tm][0]+bias) | ((u32)f2bf(acc[tm][1]+bias)<<16);
        u32 pk1 = (u32)f2bf(acc[tm][2]+bias) | ((u32)f2bf(acc[tm][3]+bias)<<16);
        *(u64*)(rowp + tm*16 + q*4) = (u64)pk0 | ((u64)pk1<<32);
      }
    }
  }
}

// ---------------- K2: triangle einsum per h + gate multiply ----------------
// T14 async-stage: loads for step s+1 issue right after step s's LDS writes, so
// global latency overlaps bar+ds_read+MFMA instead of serializing at loop top.
__global__ __launch_bounds__(512) void k_einsum(const u16* __restrict__ lr_,
    const u16* __restrict__ gate_, u16* __restrict__ og_) {
  __shared__ u16 smem[2*128*LDA];  // 36864 B
  u16* At = smem; u16* Bt = smem + 128*LDA;
  int bx = blockIdx.x;
  int wk = (bx & 7) * 144 + (bx >> 3);   // XCD-chunked bijection on 1152
  int h = wk / 9; int rem = wk % 9;
  int i0 = (rem/3)*128, j0c = rem%3;     // j0 = j0c*128
  int t = threadIdx.x, w = t>>6, lane = t&63;
  int q = lane>>4, nl = lane&15;
  f32x4_t acc[4][2] = {};
  int m0 = (w&1)*64, nb0 = (w>>1)*32;

  int rrA = t>>2, quarterA = t&3;        // A staging ids
  int kk2 = t>>4, seg = t&15;            // B staging ids

  uint4 aR0, aR1, bR0, bR1;
  { // prologue: loads for step 0 (kb=0 -> c=0, off=0)
    const u16* ga = lr_ + (((size_t)(i0+rrA)*3 + 0)*256 + h)*128 + quarterA*16;
    aR0 = ((const uint4*)ga)[0]; aR1 = ((const uint4*)ga)[1];
    const u16* g0 = lr_ + (((size_t)(2*kk2)*3 + j0c)*256 + 128 + h)*128 + seg*8;
    bR0 = ((const uint4*)g0)[0];
    bR1 = ((const uint4*)(g0 + 3*256*128))[0];
  }
  #pragma unroll 1
  for (int s = 0; s < 6; ++s) {
    { // write A tile from regs
      u16* lp = At + rrA*LDA + quarterA*16;
      ((uint4*)lp)[0] = aR0; ((uint4*)lp)[1] = aR1;
    }
    { // write B tile: register pair-transpose + XOR swizzle
      u32 w0[4] = {bR0.x,bR0.y,bR0.z,bR0.w};
      u32 w1[4] = {bR1.x,bR1.y,bR1.z,bR1.w};
      u32 sw = (u32)(seg>>1) << 4;
      char* bbytes = (char*)Bt;
      #pragma unroll
      for (int e=0;e<4;e++) {
        u32 lo = w0[e], hi = w1[e];
        u32 evenw = (lo & 0xffffu) | (hi << 16);
        u32 oddw  = (lo >> 16)     | (hi & 0xffff0000u);
        int je = seg*8 + 2*e;
        *(u32*)(bbytes + (((u32)(je*LDA + 2*kk2) * 2u) ^ sw)) = evenw;
        *(u32*)(bbytes + (((u32)((je+1)*LDA + 2*kk2) * 2u) ^ sw)) = oddw;
      }
    }
    if (s < 5) { // T14: issue next-step loads NOW (in flight through bar+MFMA+bar)
      int kb = (s+1)*64; int c = kb>>7, off = kb&127;
      const u16* ga = lr_ + (((size_t)(i0+rrA)*3 + c)*256 + h)*128 + off + quarterA*16;
      aR0 = ((const uint4*)ga)[0]; aR1 = ((const uint4*)ga)[1];
      const u16* g0 = lr_ + (((size_t)(kb + 2*kk2)*3 + j0c)*256 + 128 + h)*128 + seg*8;
      bR0 = ((const uint4*)g0)[0];
      bR1 = ((const uint4*)(g0 + 3*256*128))[0];
    }
    __syncthreads();
    #pragma unroll
    for (int ks=0; ks<2; ks++) {
      int kel = ks*32 + q*8;
      bf16x8_t a[4], b[2];
      #pragma unroll
      for (int tm=0;tm<4;tm++) a[tm] = *(const bf16x8_t*)(At + (m0+tm*16+nl)*LDA + kel);
      #pragma unroll
      for (int tn=0;tn<2;tn++) {
        u32 swr = (u32)(((nb0>>4) + tn) & 7) << 4;
        b[tn] = *(const bf16x8_t*)((const char*)Bt + ((u32)(((nb0+tn*16+nl)*LDA + kel)*2) ^ swr));
      }
      #pragma unroll
      for (int tm=0;tm<4;tm++)
        #pragma unroll
        for (int tn=0;tn<2;tn++)
          acc[tm][tn] = __builtin_amdgcn_mfma_f32_16x16x32_bf16(a[tm], b[tn], acc[tm][tn], 0,0,0);
    }
    __syncthreads();
  }
  // epilogue: acc -> LDS bf16 [m][n], then gate-multiplied coalesced store (og[rb][h][j])
  u16* Ot = smem;  // 128*LDT u16 = 34816 B <= 36864
  #pragma unroll
  for (int tm=0;tm<4;tm++)
    #pragma unroll
    for (int tn=0;tn<2;tn++)
      #pragma unroll
      for (int p=0;p<4;p++) {
        int m = m0 + tm*16 + q*4 + p;
        int n = nb0 + tn*16 + nl;
        Ot[m*LDT + n] = f2bf(acc[tm][tn][p]);
      }
  __syncthreads();
  {
    int m = t>>2, hq = t&3;
    size_t gbase = (((size_t)(i0+m)*3 + j0c)*128 + h)*128 + hq*32;
    const uint4* gg = (const uint4*)(gate_ + gbase);
    const uint4* lo = (const uint4*)(Ot + m*LDT + hq*32);
    uint4* od = (uint4*)(og_ + gbase);
    #pragma unroll
    for (int i=0;i<4;i++) {
      uint4 gv = gg[i]; uint4 ov = lo[i];
      u32 ga[4] = {gv.x,gv.y,gv.z,gv.w};
      u32 oa[4] = {ov.x,ov.y,ov.z,ov.w};
      u32 ra2[4];
      #pragma unroll
      for (int e=0;e<4;e++) {
        float g0 = bf2f((u16)(ga[e]&0xffffu)), g1 = bf2f((u16)(ga[e]>>16));
        float o0 = bf2f((u16)(oa[e]&0xffffu)), o1 = bf2f((u16)(oa[e]>>16));
        ra2[e] = (u32)f2bf(o0*g0) | ((u32)f2bf(o1*g1)<<16);
      }
      od[i] = make_uint4(ra2[0],ra2[1],ra2[2],ra2[3]);
    }
  }
}

// ---------------- K3: og @ Wo + bo + pair, rowwise LN, fp32 out ----------------
// Wt staged ONCE (full 128x128). A tile T14-prefetched; transpose uses the proven
// einsum-B pair-transpose + XOR swizzle (b32 writes, conflict-spread), read XOR = w<<4.
__global__ __launch_bounds__(512) void k_final(const u16* __restrict__ og_, const u16* __restrict__ wot,
    const float* __restrict__ pair, const float* __restrict__ bo,
    const float* __restrict__ ng, const float* __restrict__ nb_,
    float* __restrict__ out) {
  __shared__ u16 At[128*LDW];    // 18432 B
  __shared__ u16 Wt[128*LDW2];   // 34816 B
  int bx = blockIdx.x;
  int r0 = bx * 128;
  int t = threadIdx.x, w = t>>6, lane = t&63;
  int q = lane>>4, nl = lane&15;
  f32x4_t acc[8] = {};
  int m0 = w*16;
  int hh2 = t>>4, seg = t&15;    // A staging: column pair 2*hh2, r-chunk seg*8

  uint4 aR0, aR1;
  { // prologue: A(c0=0) loads
    const u16* g0 = og_ + ((size_t)bx*128 + 2*hh2)*128 + seg*8;
    aR0 = ((const uint4*)g0)[0];
    aR1 = ((const uint4*)(g0 + 128))[0];
  }
  { // stage full Wo -> Wt[c][k], once
    int c = t>>2, q4 = t&3;
    const u16* gp = wot + (size_t)c*128 + q4*32;
    u16* lp = Wt + c*LDW2 + q4*32;
    #pragma unroll
    for (int i=0;i<4;i++) ((uint4*)lp)[i] = ((const uint4*)gp)[i];
  }
  #pragma unroll
  for (int step=0; step<2; ++step) {
    { // write At from regs: pair-transpose + swizzle (cols 2hh2, 2hh2+1)
      u32 w0[4] = {aR0.x,aR0.y,aR0.z,aR0.w};
      u32 w1[4] = {aR1.x,aR1.y,aR1.z,aR1.w};
      u32 sw = (u32)(seg>>1) << 4;
      char* abytes = (char*)At;
      #pragma unroll
      for (int e=0;e<4;e++) {
        u32 lo = w0[e], hi = w1[e];
        u32 evenw = (lo & 0xffffu) | (hi << 16);
        u32 oddw  = (lo >> 16)     | (hi & 0xffff0000u);
        int je = seg*8 + 2*e;
        *(u32*)(abytes + (((u32)(je*LDW + 2*hh2) * 2u) ^ sw)) = evenw;
        *(u32*)(abytes + (((u32)((je+1)*LDW + 2*hh2) * 2u) ^ sw)) = oddw;
      }
    }
    if (step == 0) { // T14: prefetch A(c0=64) during step 0's MFMA
      const u16* g0 = og_ + ((size_t)bx*128 + 64 + 2*hh2)*128 + seg*8;
      aR0 = ((const uint4*)g0)[0];
      aR1 = ((const uint4*)(g0 + 128))[0];
    }
    __syncthreads();
    int c0 = step*64;
    #pragma unroll
    for (int ks=0; ks<2; ks++) {
      int kel = ks*32 + q*8;
      bf16x8_t a = *(const bf16x8_t*)((const char*)At +
                     ((u32)(((m0+nl)*LDW + kel)*2) ^ ((u32)w << 4)));
      bf16x8_t b[8];
      #pragma unroll
      for (int tn=0;tn<8;tn++) b[tn] = *(const bf16x8_t*)(Wt + (tn*16+nl)*LDW2 + c0 + kel);
      #pragma unroll
      for (int tn=0;tn<8;tn++)
        acc[tn] = __builtin_amdgcn_mfma_f32_16x16x32_bf16(a, b[tn], acc[tn], 0,0,0);
    }
    __syncthreads();
  }
  // epilogue: residual + bias, transpose-free rowwise LN via 16-lane shfl reduction
  float rsum[4], rsq[4];
  #pragma unroll
  for (int p=0;p<4;p++) { rsum[p]=0.f; rsq[p]=0.f; }
  #pragma unroll
  for (int tn=0;tn<8;tn++) {
    int n = tn*16 + nl;
    float bb = bo[n];
    #pragma unroll
    for (int p=0;p<4;p++) {
      int m = m0 + q*4 + p;
      float v = acc[tn][p] + bb + pair[(size_t)(r0+m)*128 + n];
      acc[tn][p] = v;
      rsum[p] += v;
      rsq[p]  += v*v;
    }
  }
  #pragma unroll
  for (int msk=1; msk<16; msk<<=1) {
    #pragma unroll
    for (int p=0;p<4;p++) {
      rsum[p] += __shfl_xor(rsum[p], msk, 64);
      rsq[p]  += __shfl_xor(rsq[p],  msk, 64);
    }
  }
  #pragma unroll
  for (int p=0;p<4;p++) {
    float mu = rsum[p] * (1.f/128.f);
    float var = rsq[p]*(1.f/128.f) - mu*mu;
    rsum[p] = mu;
    rsq[p] = rsqrtf(var + 1e-5f);
  }
  #pragma unroll
  for (int tn=0;tn<8;tn++) {
    int n = tn*16 + nl;
    float g = ng[n], b2 = nb_[n];
    #pragma unroll
    for (int p=0;p<4;p++) {
      int m = m0 + q*4 + p;
      out[(size_t)(r0+m)*128 + n] = (acc[tn][p] - rsum[p]) * rsq[p] * g + b2;
    }
  }
}

extern "C" void kernel_launch(void* const* d_in, const int* in_sizes, int n_in,
                              void* d_out, int out_size, void* d_ws, size_t ws_size,
                              hipStream_t stream) {
  (void)in_sizes; (void)n_in; (void)out_size; (void)ws_size;
  const float* pair   = (const float*)d_in[0];
  const float* ln_l_g = (const float*)d_in[1];
  const float* ln_l_b = (const float*)d_in[2];
  const float* ln_r_g = (const float*)d_in[3];
  const float* ln_r_b = (const float*)d_in[4];
  const float* Wl = (const float*)d_in[5];
  const float* bl = (const float*)d_in[6];
  const float* Wr = (const float*)d_in[7];
  const float* br = (const float*)d_in[8];
  const float* Wg = (const float*)d_in[9];
  const float* bg = (const float*)d_in[10];
  const float* Wo = (const float*)d_in[11];
  const float* bo = (const float*)d_in[12];
  const float* n_g = (const float*)d_in[13];
  const float* n_b = (const float*)d_in[14];

  char* ws = (char*)d_ws;
  const size_t SZ = (size_t)M_*128*sizeof(u16);         // 37,748,736 B
  u16*  og    = (u16*)(ws);                             // [1152][128][128]
  u16*  gate  = (u16*)(ws + SZ);                        // [1152][128][128]
  u16*  wcat  = (u16*)(ws + 2*SZ);
  float* bcat = (float*)(ws + 2*SZ + 98304);
  float* sgp  = (float*)(ws + 2*SZ + 98304 + 1536);
  u16*  wot   = (u16*)(ws + 2*SZ + 98304 + 1536 + 512);

  // lr[1152][256][128] (left|right cat) lives in d_out (exactly M_*128*4 B),
  // consumed by k_einsum before k_final overwrites d_out with the fp32 result.
  u16* lr = (u16*)d_out;

  k_prep<<<258, 256, 0, stream>>>(ln_l_g, ln_r_g, Wl, Wr, Wg, Wo,
                                  ln_l_b, ln_r_b, bl, br, bg, wcat, wot, bcat, sgp);
  k_projln<<<1152, 512, 0, stream>>>(pair, wcat, bcat, sgp, lr, gate);
  k_einsum<<<1152, 512, 0, stream>>>(lr, gate, og);
  k_final<<<1152, 512, 0, stream>>>(og, wot, pair, bo, n_g, n_b, (float*)d_out);
}